// Round 11
// baseline (297.192 us; speedup 1.0000x reference)
//
#include <hip/hip_runtime.h>

// DiffPooling on MI355X (gfx950).
// outputs f32 concat: features_pooled (256x512), assignments (8192x256),
// adjacency_pooled (256x256), link_loss, ent_loss.
// link_loss: ||A - sp sp^T||_F^2 = sum(A^2) - 2*tr(adj_pooled) + ||sp^T sp||_F^2
//
// MFMA A-operands in "panel" format (stride-32 u16 rows, gll-linear):
//   offset_u16(p, m, k) = (p*256 + m)*32 + (k%32),  p = global_k/32
// G2 writes bf16 partials DIRECTLY as panels; G3 consumes the 8 parts as one
// Kin=65536 panel-A GEMM with B-row = kq & 8191 (linearity of A_pool).
// gemm2 pipeline: 2-deep B prefetch (rbE/rbO), counted vmcnt(20), LDS dbuf.

typedef unsigned short u16;
typedef __bf16 bf16x8 __attribute__((ext_vector_type(8)));
typedef float f32x4 __attribute__((ext_vector_type(4)));
typedef float float8_t __attribute__((ext_vector_type(8)));
typedef unsigned short ushort8_t __attribute__((ext_vector_type(8)));

#define Nn 8192
#define Dd 512
#define Kk 256

__device__ __forceinline__ u16 f2bf(float f) {
  unsigned int u = __builtin_bit_cast(unsigned int, f);
  u += 0x7FFFu + ((u >> 16) & 1u);   // RNE
  return (u16)(u >> 16);
}
__device__ __forceinline__ void gll16(const void* g, void* l) {
  __builtin_amdgcn_global_load_lds(
      (const __attribute__((address_space(1))) unsigned int*)g,
      (__attribute__((address_space(3))) unsigned int*)l, 16, 0, 0);
}

template <bool B> struct BRegSel { typedef float8_t T; };
template <> struct BRegSel<true> { typedef ushort8_t T; };

// ---------------- panel-A bf16 MFMA GEMM, 2-deep counted-vmcnt pipeline ----------
// C(256 x 64 per block) = Apanel @ B(row-major, ldb; f32->bf16 on the fly if !BF16B)
// 256 threads / 4 waves, wave tile 64x64, BK=32, LDS dbuf, 40960 B.
// Phase (tile t, buf c): gllA(1-c, t+1)[4] ; storeB(c, rb_t) [implicit vmcnt(12)] ;
//   loadB(rb, t+2)[8] ; vmcnt(20) lgkmcnt(0) ; barrier ; MFMA(c) ; barrier.
// Steady state keeps 20 newest in flight: rb(t+1)8 + gllA(t+1)4 + rb(t+2)8;
// drains gllA(t) (older). B loads get ~2 comp phases of latency cover.
// OUTKIND: 0 = f32 store via LDS at Cv + bz*zstride, 1 = bf16 PANEL partial (G2).
template <bool BF16B, bool SUMSQ, bool MODB, int OUTKIND, int OCC>
__launch_bounds__(256, OCC)
__global__ void gemm2(const u16* __restrict__ Apan, int ppmb,
                      const void* __restrict__ Bv, int ldb,
                      void* __restrict__ Cv, int ldc,
                      int kchunk, size_t zstride,
                      float* __restrict__ sumsq, int swz) {
  __shared__ alignas(16) u16 SH[2 * 8192 + 2 * 2048];  // 40960 B exactly
  float* sred = (float*)&SH[20472];                    // last 16 B

  int bx = blockIdx.x, bz = blockIdx.z;
  if (swz) {  // XCD-chunked bijective remap (total % 8 == 0)
    int gx = gridDim.x, tot = gx * gridDim.z;
    int f = bx + gx * bz;
    int l = (f & 7) * (tot >> 3) + (f >> 3);
    bx = l % gx; bz = l / gx;
  }
  const int tid = threadIdx.x, wv = tid >> 6, lane = tid & 63;
  const int l15 = lane & 15, g = lane >> 4;
  const int col0 = bx * 64;
  const int row0 = blockIdx.y * 256;
  const int kbeg = bz * kchunk;
  const int steps = kchunk >> 5;                       // always even here
  const u16* pbase = Apan + (size_t)(blockIdx.y * ppmb + (kbeg >> 5)) * 8192;

  float ss = 0.f;
  typename BRegSel<BF16B>::T rbE, rbO;

  auto loadB = [&](auto& rb, int t) {   // thread owns column (col0+lane), rows wv*8..+7
    int kq = kbeg + t * 32 + wv * 8;
    if constexpr (MODB) kq &= (Nn - 1);
    if constexpr (BF16B) {
      const u16* p = (const u16*)Bv + (size_t)kq * ldb + col0 + lane;
#pragma unroll
      for (int i = 0; i < 8; ++i) rb[i] = p[(size_t)i * ldb];
    } else {
      const float* p = (const float*)Bv + (size_t)kq * ldb + col0 + lane;
#pragma unroll
      for (int i = 0; i < 8; ++i) rb[i] = p[(size_t)i * ldb];
    }
  };
  auto storeB = [&](int buf, auto& rb) {  // pack 8 k-elems of one col -> one b128
    ushort8_t h;
    if constexpr (BF16B) {
      h = rb;
    } else {
#pragma unroll
      for (int i = 0; i < 8; ++i) {
        h[i] = f2bf(rb[i]);
        if constexpr (SUMSQ) ss += rb[i] * rb[i];
      }
    }
    *(uint4*)&SH[16384 + buf * 2048 + lane * 32 + wv * 8] = __builtin_bit_cast(uint4, h);
  };
  auto gllA = [&](int buf, int t) {      // 16 KB panel tile -> LDS, linear, coalesced
    const char* gp = (const char*)(pbase + (size_t)t * 8192) + wv * 4096 + lane * 16;
    char* lp = (char*)&SH[buf * 8192] + wv * 4096;
#pragma unroll
    for (int r = 0; r < 4; ++r) gll16(gp + r * 1024, lp + r * 1024);
  };

  f32x4 acc[4][4];
#pragma unroll
  for (int i = 0; i < 4; ++i)
#pragma unroll
    for (int j = 0; j < 4; ++j) acc[i][j] = (f32x4){0.f, 0.f, 0.f, 0.f};

  auto comp = [&](int buf) {
    const u16* as = &SH[buf * 8192];
    const u16* bs = &SH[16384 + buf * 2048];
    bf16x8 afr[4], bfr[4];
#pragma unroll
    for (int j = 0; j < 4; ++j)
      bfr[j] = *(const bf16x8*)(bs + (j * 16 + l15) * 32 + g * 8);
#pragma unroll
    for (int i = 0; i < 4; ++i)
      afr[i] = *(const bf16x8*)(as + (wv * 64 + i * 16 + l15) * 32 + g * 8);
#pragma unroll
    for (int i = 0; i < 4; ++i)
#pragma unroll
      for (int j = 0; j < 4; ++j)
        acc[i][j] = __builtin_amdgcn_mfma_f32_16x16x32_bf16(afr[i], bfr[j], acc[i][j], 0, 0, 0);
  };

  // prologue: A(0) + B(0) + B(1) in flight
  gllA(0, 0);
  loadB(rbE, 0);
  loadB(rbO, 1);
  const int last = steps - 1;

  for (int t = 0; t < steps; t += 2) {
    // even phase: tile t in buf0
    gllA(1, (t + 1 < last) ? t + 1 : last);
    storeB(0, rbE);                       // implicit wait drains B(t) (+A(t))
    loadB(rbE, (t + 2 < last) ? t + 2 : last);
    asm volatile("s_waitcnt vmcnt(20) lgkmcnt(0)" ::: "memory");
    __builtin_amdgcn_s_barrier();
    __builtin_amdgcn_sched_barrier(0);
    comp(0);
    __builtin_amdgcn_sched_barrier(0);
    __builtin_amdgcn_s_barrier();
    // odd phase: tile t+1 in buf1
    gllA(0, (t + 2 < last) ? t + 2 : last);
    storeB(1, rbO);
    loadB(rbO, (t + 3 < last) ? t + 3 : last);
    asm volatile("s_waitcnt vmcnt(20) lgkmcnt(0)" ::: "memory");
    __builtin_amdgcn_s_barrier();
    __builtin_amdgcn_sched_barrier(0);
    comp(1);
    __builtin_amdgcn_sched_barrier(0);
    __builtin_amdgcn_s_barrier();
  }
  // full drain before LDS reuse in epilogues
  asm volatile("s_waitcnt vmcnt(0) lgkmcnt(0)" ::: "memory");
  __builtin_amdgcn_s_barrier();

  // epilogues (C/D layout m89-verified: col = j*16+l15, row = wv*64+i*16+g*4+r)
  if constexpr (OUTKIND == 0) {          // f32 via LDS, two 128-row halves
    float* Cz = (float*)Cv + (size_t)bz * zstride;
    float* sf = (float*)SH;              // [128][68] f32
#pragma unroll
    for (int h = 0; h < 2; ++h) {
      __syncthreads();
      if ((wv >> 1) == h) {
#pragma unroll
        for (int i = 0; i < 4; ++i)
#pragma unroll
          for (int j = 0; j < 4; ++j)
#pragma unroll
            for (int r = 0; r < 4; ++r)
              sf[((wv & 1) * 64 + i * 16 + g * 4 + r) * 68 + j * 16 + l15] = acc[i][j][r];
      }
      __syncthreads();
#pragma unroll
      for (int e = 0; e < 8; ++e) {     // 2048 float4s = full 128x64 tile
        int idx2 = tid + e * 256;
        int m = idx2 >> 4, c4 = (idx2 & 15) * 4;
        float4 v = *(const float4*)(sf + m * 68 + c4);
        *(float4*)(Cz + (size_t)(row0 + h * 128 + m) * ldc + col0 + c4) = v;
      }
    }
  } else {                               // bf16 PANEL partial (G2)
    u16* C = (u16*)Cv + (size_t)bz * zstride;
    u16* sb = SH;                        // [256][72] u16
#pragma unroll
    for (int i = 0; i < 4; ++i)
#pragma unroll
      for (int j = 0; j < 4; ++j)
#pragma unroll
        for (int r = 0; r < 4; ++r)
          sb[(wv * 64 + i * 16 + g * 4 + r) * 72 + j * 16 + l15] = f2bf(acc[i][j][r]);
    __syncthreads();
    int c8 = tid & 7;
    size_t pb = (size_t)((col0 >> 5) + (c8 >> 2)) * 8192 + (c8 & 3) * 8;
#pragma unroll
    for (int e = 0; e < 8; ++e) {
      int m = (tid >> 3) + e * 32;
      uint4 v = *(const uint4*)(sb + m * 72 + c8 * 8);
      *(uint4*)(C + pb + (size_t)m * 32) = v;
    }
  }

  if constexpr (SUMSQ) {
#pragma unroll
    for (int o = 32; o; o >>= 1) ss += __shfl_xor(ss, o);
    __syncthreads();
    if (lane == 0) sred[wv] = ss;
    __syncthreads();
    if (tid == 0) atomicAdd(sumsq, sred[0] + sred[1] + sred[2] + sred[3]);
  }
}

// ---------------- producers / small kernels ----------------
// F f32 -> panel bf16; extra last block zeroes cs + scal (incl. finalize counter)
__launch_bounds__(256)
__global__ void cvtF_panel(const float* __restrict__ F, u16* __restrict__ pan,
                           float* __restrict__ cs, float* __restrict__ scal) {
  if (blockIdx.x == 2048) {
    int t = threadIdx.x;
    float4 z = {0.f, 0.f, 0.f, 0.f};
    if (t < 64) ((float4*)cs)[t] = z;
    else if (t < 66) ((float4*)scal)[t - 64] = z;   // scal[0..7]
    return;
  }
  int idx = blockIdx.x * 256 + threadIdx.x;
  int m = idx >> 6, k0 = (idx & 63) * 8;
  float4 a = *(const float4*)(F + (size_t)m * Dd + k0);
  float4 b = *(const float4*)(F + (size_t)m * Dd + k0 + 4);
  ushort8_t h;
  h[0] = f2bf(a.x); h[1] = f2bf(a.y); h[2] = f2bf(a.z); h[3] = f2bf(a.w);
  h[4] = f2bf(b.x); h[5] = f2bf(b.y); h[6] = f2bf(b.z); h[7] = f2bf(b.w);
  int mb = m >> 8, mr = m & 255, p = k0 >> 5, c = k0 & 31;
  *(uint4*)(pan + ((size_t)(mb * 16 + p) * 256 + mr) * 32 + c) = __builtin_bit_cast(uint4, h);
}

// wave-per-row softmax: block = 4 waves = 4 rows; lane holds 4 cols (float4).
__launch_bounds__(256)
__global__ void softmax_rows(float* __restrict__ io, const float* __restrict__ bias) {
  int wv = threadIdx.x >> 6, lane = threadIdx.x & 63;
  int n = blockIdx.x * 4 + wv;
  float4 b4 = ((const float4*)bias)[lane];
  float4 x = ((const float4*)(io + (size_t)n * Kk))[lane];
  x.x += b4.x; x.y += b4.y; x.z += b4.z; x.w += b4.w;
  float m = fmaxf(fmaxf(x.x, x.y), fmaxf(x.z, x.w));
#pragma unroll
  for (int o = 32; o; o >>= 1) m = fmaxf(m, __shfl_xor(m, o));
  float4 e = {__expf(x.x - m), __expf(x.y - m), __expf(x.z - m), __expf(x.w - m)};
  float s = e.x + e.y + e.z + e.w;
#pragma unroll
  for (int o = 32; o; o >>= 1) s += __shfl_xor(s, o);
  float inv = 1.f / s;
  e.x *= inv; e.y *= inv; e.z *= inv; e.w *= inv;
  ((float4*)(io + (size_t)n * Kk))[lane] = e;
}

__launch_bounds__(256)
__global__ void colsum_k(const float* __restrict__ a, float* __restrict__ cs) {
  __shared__ float4 red[4][64];
  int t = threadIdx.x, rg = t >> 6, c = t & 63;
  size_t n0 = (size_t)blockIdx.x * 128 + rg * 32;
  float4 s = {0.f, 0.f, 0.f, 0.f};
  for (int i = 0; i < 32; ++i) {
    float4 v = ((const float4*)(a + (n0 + i) * Kk))[c];
    s.x += v.x; s.y += v.y; s.z += v.z; s.w += v.w;
  }
  red[rg][c] = s;
  __syncthreads();
  if (rg == 0) {
    float4 a1 = red[1][c], a2 = red[2][c], a3 = red[3][c];
    s.x += a1.x + a2.x + a3.x; s.y += a1.y + a2.y + a3.y;
    s.z += a1.z + a2.z + a3.z; s.w += a1.w + a2.w + a3.w;
    atomicAdd(&cs[c * 4 + 0], s.x); atomicAdd(&cs[c * 4 + 1], s.y);
    atomicAdd(&cs[c * 4 + 2], s.z); atomicAdd(&cs[c * 4 + 3], s.w);
  }
}

// fused: sp (bf16 row-major) + spT panel + entropy. block p: rows [32p,32p+32).
__launch_bounds__(256)
__global__ void make_sp_all(const float* __restrict__ a, const float* __restrict__ cs,
                            u16* __restrict__ spb, u16* __restrict__ pan,
                            float* __restrict__ ent_sum) {
  __shared__ float sr[4];
  int p = blockIdx.x, k = threadIdx.x;
  float inv = 1.f / (cs[k] + 1e-8f);
  int n0 = p * 32;
  float ent = 0.f;
  ushort8_t h[4];
#pragma unroll
  for (int q = 0; q < 4; ++q) {
#pragma unroll
    for (int j = 0; j < 8; ++j) {
      float v = a[(size_t)(n0 + q * 8 + j) * Kk + k] * inv;
      u16 hb = f2bf(v);
      h[q][j] = hb;
      ent -= v * __logf(v + 1e-15f);
      spb[(size_t)(n0 + q * 8 + j) * Kk + k] = hb;
    }
  }
  u16* dst = pan + ((size_t)p * 256 + k) * 32;
  *(uint4*)(dst + 0)  = __builtin_bit_cast(uint4, h[0]);
  *(uint4*)(dst + 8)  = __builtin_bit_cast(uint4, h[1]);
  *(uint4*)(dst + 16) = __builtin_bit_cast(uint4, h[2]);
  *(uint4*)(dst + 24) = __builtin_bit_cast(uint4, h[3]);
#pragma unroll
  for (int o = 32; o; o >>= 1) ent += __shfl_xor(ent, o);
  if ((k & 63) == 0) sr[k >> 6] = ent;
  __syncthreads();
  if (k == 0) atomicAdd(ent_sum, sr[0] + sr[1] + sr[2] + sr[3]);
}

// combine partials + inline finalize (last-block pattern).
// blocks 0-511: fpool (16); 512-767: frob(spTsp) (16); 768-1023: apool (32) + trace.
__launch_bounds__(256)
__global__ void combine3(const float* __restrict__ fp_part, const float* __restrict__ ss_part,
                         const float* __restrict__ ap_part,
                         float* __restrict__ fpool, float* __restrict__ apool,
                         float* __restrict__ scal,
                         float* __restrict__ olink, float* __restrict__ oent) {
  __shared__ float sr[4];
  __shared__ int lastS;
  int b = blockIdx.x, t = threadIdx.x;
  if (b < 512) {
    int i = b * 256 + t;
    float s = 0.f;
#pragma unroll
    for (int z = 0; z < 16; ++z) s += fp_part[z * 131072 + i];
    fpool[i] = s;
  } else if (b < 768) {
    int i = (b - 512) * 256 + t;
    float s = 0.f;
#pragma unroll
    for (int z = 0; z < 16; ++z) s += ss_part[z * 65536 + i];
    float q = s * s;
#pragma unroll
    for (int o = 32; o; o >>= 1) q += __shfl_xor(q, o);
    if ((t & 63) == 0) sr[t >> 6] = q;
    __syncthreads();
    if (t == 0) atomicAdd(&scal[2], sr[0] + sr[1] + sr[2] + sr[3]);
  } else {
    int i = (b - 768) * 256 + t;
    float s = 0.f;
#pragma unroll
    for (int z = 0; z < 32; ++z) s += ap_part[z * 65536 + i];
    apool[i] = s;
    if (i % 257 == 0) atomicAdd(&scal[3], s);
  }
  __threadfence();
  if (t == 0) {
    int* cnt = (int*)&scal[4];
    lastS = (atomicAdd(cnt, 1) == 1023);
  }
  __syncthreads();
  if (lastS && t == 0) {
    __threadfence();
    volatile float* sc = scal;
    float val = sc[0] - 2.f * sc[3] + sc[2];
    *olink = sqrtf(fmaxf(val, 0.f)) / ((float)Nn * (float)Nn);
    *oent  = sc[1] / (float)Nn;
  }
}

// ---------------- launch ----------------
extern "C" void kernel_launch(void* const* d_in, const int* in_sizes, int n_in,
                              void* d_out, int out_size, void* d_ws, size_t ws_size,
                              hipStream_t stream) {
  const float* F    = (const float*)d_in[0];
  const float* Adj  = (const float*)d_in[1];
  const float* W    = (const float*)d_in[2];
  const float* bias = (const float*)d_in[3];
  float* out = (float*)d_out;
  char* ws = (char*)d_ws;

  u16*  FbfPan  = (u16*)(ws + 0);            // 8 MB (dead after G1)
  u16*  parts   = (u16*)(ws + 0);            // 8 x 4 MB bf16 G2 panel-partials
  u16*  spb     = (u16*)(ws + 33554432);     // 4 MB
  u16*  spTpan  = (u16*)(ws + 37748736);     // 4 MB
  float* fp_part = (float*)(ws + 41943040);  // 8 MB (16 x 131072)
  float* ss_part = (float*)(ws + 50331648);  // 4 MB (16 x 65536)
  float* ap_part = (float*)(ws + 54525952);  // 8 MB (32 x 65536)
  float* cs     = (float*)(ws + 62914560);   // 1 KB
  float* scal   = (float*)(ws + 62915584);   // [0]sumA2 [1]ent [2]frob [3]trace [4]cnt

  float* fpool  = out;
  float* assign = out + 131072;
  float* apool  = out + 2228224;
  float* olink  = out + 2293760;
  float* oent   = out + 2293761;

  cvtF_panel<<<2049, 256, 0, stream>>>(F, FbfPan, cs, scal);

  // G1: logits = F @ W -> assign, softmax in place
  gemm2<false, false, false, 0, 2><<<dim3(4, 32, 1), 256, 0, stream>>>(
      FbfPan, 16, W, Kk, assign, Kk, Dd, 0, nullptr, 0);
  softmax_rows<<<2048, 256, 0, stream>>>(assign, bias);
  colsum_k<<<64, 256, 0, stream>>>(assign, cs);
  make_sp_all<<<256, 256, 0, stream>>>(assign, cs, spb, spTpan, &scal[1]);

  // G4: fp_part = spT @ F (16 z-chunks, plain f32 stores)
  gemm2<false, false, false, 0, 2><<<dim3(8, 1, 16), 256, 0, stream>>>(
      spTpan, 256, F, Dd, fp_part, Dd, Nn / 16, 131072, nullptr, 1);
  // G5: ss_part = spT @ sp
  gemm2<true, false, false, 0, 2><<<dim3(4, 1, 16), 256, 0, stream>>>(
      spTpan, 256, spb, Kk, ss_part, Kk, Nn / 16, 65536, nullptr, 1);
  // G2: P panel-partials = spT @ A + fused sum(A^2); XCD-chunked, 4 blk/CU
  gemm2<false, true, false, 1, 4><<<dim3(128, 1, 8), 256, 0, stream>>>(
      spTpan, 256, Adj, Nn, parts, Nn, Nn / 8, (size_t)Kk * Nn, &scal[0], 1);
  // G3: apool partials = [parts] @ [sp;...;sp]  (Kin=65536, B-row = kq & 8191)
  gemm2<true, false, true, 0, 2><<<dim3(4, 1, 32), 256, 0, stream>>>(
      parts, 0, spb, Kk, ap_part, Kk, 65536 / 32, 65536, nullptr, 1);

  combine3<<<1024, 256, 0, stream>>>(fp_part, ss_part, ap_part, fpool, apool,
                                     scal, olink, oent);
}

// Round 12
// 267.163 us; speedup vs baseline: 1.1124x; 1.1124x over previous
//
#include <hip/hip_runtime.h>

// DiffPooling on MI355X (gfx950).
// outputs f32 concat: features_pooled (256x512), assignments (8192x256),
// adjacency_pooled (256x256), link_loss, ent_loss.
// link_loss: ||A - sp sp^T||_F^2 = sum(A^2) - 2*tr(adj_pooled) + ||sp^T sp||_F^2
//
// MFMA A-operands in "panel" format (stride-32 u16 rows, gll-linear):
//   offset_u16(p, m, k) = (p*256 + m)*32 + (k%32),  p = global_k/32
// Key identity: sp = assign * inv_cs(col) is a COLUMN scaling -> fold into
// combine3. All GEMM B-operands are then f32 (Adj, F, assign): one hot path.
// mega = G4(128 blocks) + G5(64) + G2(1024, XCD-chunked): G4/G5 first, G2
// overlaps them. G2 writes bf16 partials directly as panels; G3 = parts
// (Kin=65536, B-row = kq & 8191) with z=64 for pipeline depth.

typedef unsigned short u16;
typedef __bf16 bf16x8 __attribute__((ext_vector_type(8)));
typedef float f32x4 __attribute__((ext_vector_type(4)));
typedef float float8_t __attribute__((ext_vector_type(8)));
typedef unsigned short ushort8_t __attribute__((ext_vector_type(8)));

#define Nn 8192
#define Dd 512
#define Kk 256

__device__ __forceinline__ u16 f2bf(float f) {
  unsigned int u = __builtin_bit_cast(unsigned int, f);
  u += 0x7FFFu + ((u >> 16) & 1u);   // RNE
  return (u16)(u >> 16);
}
__device__ __forceinline__ void gll16(const void* g, void* l) {
  __builtin_amdgcn_global_load_lds(
      (const __attribute__((address_space(1))) unsigned int*)g,
      (__attribute__((address_space(3))) unsigned int*)l, 16, 0, 0);
}

// ---------------- panel-A GEMM (G1, G3), f32 B, R8 pipeline ----------------
// C(256 x 64 per block) = Apanel @ B(row-major f32, ldb; bf16 on the fly)
// Per step t: gllA(other, t+1)[4] ; storeB(cur) [implicit wait] ; loadB(t+1)[8] ;
//             vmcnt(12) lgkmcnt(0) ; barrier ; MFMA(cur) ; barrier.
template <bool MODB, int OCC>
__launch_bounds__(256, OCC)
__global__ void gemm2(const u16* __restrict__ Apan, int ppmb,
                      const float* __restrict__ Bv, int ldb,
                      float* __restrict__ Cv, int ldc,
                      int kchunk, size_t zstride, int swz) {
  __shared__ alignas(16) u16 SH[2 * 8192 + 2 * 2048];  // 40960 B

  int bx = blockIdx.x, bz = blockIdx.z;
  if (swz) {  // XCD-chunked bijective remap (total % 8 == 0)
    int gx = gridDim.x, tot = gx * gridDim.z;
    int f = bx + gx * bz;
    int l = (f & 7) * (tot >> 3) + (f >> 3);
    bx = l % gx; bz = l / gx;
  }
  const int tid = threadIdx.x, wv = tid >> 6, lane = tid & 63;
  const int l15 = lane & 15, g = lane >> 4;
  const int col0 = bx * 64;
  const int row0 = blockIdx.y * 256;
  const int kbeg = bz * kchunk;
  const int steps = kchunk >> 5;
  const u16* pbase = Apan + (size_t)(blockIdx.y * ppmb + (kbeg >> 5)) * 8192;

  float8_t rb;

  auto loadB = [&](int t) {
    int kq = kbeg + t * 32 + wv * 8;
    if constexpr (MODB) kq &= (Nn - 1);
    const float* p = Bv + (size_t)kq * ldb + col0 + lane;
#pragma unroll
    for (int i = 0; i < 8; ++i) rb[i] = p[(size_t)i * ldb];
  };
  auto storeB = [&](int buf) {
    ushort8_t h;
#pragma unroll
    for (int i = 0; i < 8; ++i) h[i] = f2bf(rb[i]);
    *(uint4*)&SH[16384 + buf * 2048 + lane * 32 + wv * 8] = __builtin_bit_cast(uint4, h);
  };
  auto gllA = [&](int buf, int t) {
    const char* gp = (const char*)(pbase + (size_t)t * 8192) + wv * 4096 + lane * 16;
    char* lp = (char*)&SH[buf * 8192] + wv * 4096;
#pragma unroll
    for (int r = 0; r < 4; ++r) gll16(gp + r * 1024, lp + r * 1024);
  };

  f32x4 acc[4][4];
#pragma unroll
  for (int i = 0; i < 4; ++i)
#pragma unroll
    for (int j = 0; j < 4; ++j) acc[i][j] = (f32x4){0.f, 0.f, 0.f, 0.f};

  auto comp = [&](int buf) {
    const u16* as = &SH[buf * 8192];
    const u16* bs = &SH[16384 + buf * 2048];
    bf16x8 afr[4], bfr[4];
#pragma unroll
    for (int j = 0; j < 4; ++j)
      bfr[j] = *(const bf16x8*)(bs + (j * 16 + l15) * 32 + g * 8);
#pragma unroll
    for (int i = 0; i < 4; ++i)
      afr[i] = *(const bf16x8*)(as + (wv * 64 + i * 16 + l15) * 32 + g * 8);
#pragma unroll
    for (int i = 0; i < 4; ++i)
#pragma unroll
      for (int j = 0; j < 4; ++j)
        acc[i][j] = __builtin_amdgcn_mfma_f32_16x16x32_bf16(afr[i], bfr[j], acc[i][j], 0, 0, 0);
  };

  gllA(0, 0);
  loadB(0);
  const int last = steps - 1;
  for (int t = 0; t < steps; ++t) {
    const int cur = t & 1;
    gllA(1 - cur, (t + 1 < last) ? t + 1 : last);
    storeB(cur);
    loadB((t + 1 < last) ? t + 1 : last);
    asm volatile("s_waitcnt vmcnt(12) lgkmcnt(0)" ::: "memory");
    __builtin_amdgcn_s_barrier();
    __builtin_amdgcn_sched_barrier(0);
    comp(cur);
    __builtin_amdgcn_sched_barrier(0);
    __builtin_amdgcn_s_barrier();
  }
  asm volatile("s_waitcnt vmcnt(0) lgkmcnt(0)" ::: "memory");
  __builtin_amdgcn_s_barrier();

  // f32 store via LDS, two 128-row halves (C/D layout m89-verified)
  float* Cz = Cv + (size_t)bz * zstride;
  float* sf = (float*)SH;              // [128][68] f32
#pragma unroll
  for (int h = 0; h < 2; ++h) {
    __syncthreads();
    if ((wv >> 1) == h) {
#pragma unroll
      for (int i = 0; i < 4; ++i)
#pragma unroll
        for (int j = 0; j < 4; ++j)
#pragma unroll
          for (int r = 0; r < 4; ++r)
            sf[((wv & 1) * 64 + i * 16 + g * 4 + r) * 68 + j * 16 + l15] = acc[i][j][r];
    }
    __syncthreads();
#pragma unroll
    for (int e = 0; e < 8; ++e) {
      int idx2 = tid + e * 256;
      int m = idx2 >> 4, c4 = (idx2 & 15) * 4;
      float4 v = *(const float4*)(sf + m * 68 + c4);
      *(float4*)(Cz + (size_t)(row0 + h * 128 + m) * ldc + col0 + c4) = v;
    }
  }
}

// ---------------- mega: G4 (b<128) + G5 (b<192) + G2 (b>=192) ----------------
// ONE f32-B hot path (identical to gemm2); role decides setup + cold epilogue.
__launch_bounds__(256, 4)
__global__ void gemm_mega(const u16* __restrict__ spTpan,
                          const float* __restrict__ Adj, u16* __restrict__ parts,
                          float* __restrict__ sumsq,
                          const float* __restrict__ F, float* __restrict__ fp_part,
                          const float* __restrict__ assign, float* __restrict__ ss_part) {
  __shared__ alignas(16) u16 SH[2 * 8192 + 2 * 2048];
  float* sred = (float*)&SH[20472];

  const int b = blockIdx.x;
  int role, bx, bz, ldb, kchunk;
  const float* Bf;
  if (b < 128) {                        // G4: fp_part = spT @ F
    role = 1; bx = b & 7; bz = b >> 3;
    Bf = F; ldb = Dd; kchunk = 512;
  } else if (b < 192) {                 // G5: ss_part(raw) = spT @ assign
    role = 2; int lb = b - 128; bx = lb & 3; bz = lb >> 2;
    Bf = assign; ldb = Kk; kchunk = 512;
  } else {                              // G2: P panel-partials = spT @ Adj
    role = 0; int bp = b - 192;
    int l = (bp & 7) * 128 + (bp >> 3); // XCD-chunked: XCD r owns z-chunk r
    bx = l & 127; bz = l >> 7;
    Bf = Adj; ldb = Nn; kchunk = 1024;
  }
  const int tid = threadIdx.x, wv = tid >> 6, lane = tid & 63;
  const int l15 = lane & 15, g = lane >> 4;
  const int col0 = bx * 64;
  const int kbeg = bz * kchunk;
  const int steps = kchunk >> 5;
  const u16* pbase = spTpan + (size_t)(kbeg >> 5) * 8192;

  float ss = 0.f;
  float8_t rb;

  auto loadB = [&](int t) {
    const int kq = kbeg + t * 32 + wv * 8;
    const float* p = Bf + (size_t)kq * ldb + col0 + lane;
#pragma unroll
    for (int i = 0; i < 8; ++i) rb[i] = p[(size_t)i * ldb];
  };
  auto storeB = [&](int buf) {
    ushort8_t h;
#pragma unroll
    for (int i = 0; i < 8; ++i) {
      h[i] = f2bf(rb[i]);
      ss += rb[i] * rb[i];               // unconditional; only role 0 commits
    }
    *(uint4*)&SH[16384 + buf * 2048 + lane * 32 + wv * 8] = __builtin_bit_cast(uint4, h);
  };
  auto gllA = [&](int buf, int t) {
    const char* gp = (const char*)(pbase + (size_t)t * 8192) + wv * 4096 + lane * 16;
    char* lp = (char*)&SH[buf * 8192] + wv * 4096;
#pragma unroll
    for (int r = 0; r < 4; ++r) gll16(gp + r * 1024, lp + r * 1024);
  };

  f32x4 acc[4][4];
#pragma unroll
  for (int i = 0; i < 4; ++i)
#pragma unroll
    for (int j = 0; j < 4; ++j) acc[i][j] = (f32x4){0.f, 0.f, 0.f, 0.f};

  auto comp = [&](int buf) {
    const u16* as = &SH[buf * 8192];
    const u16* bs = &SH[16384 + buf * 2048];
    bf16x8 afr[4], bfr[4];
#pragma unroll
    for (int j = 0; j < 4; ++j)
      bfr[j] = *(const bf16x8*)(bs + (j * 16 + l15) * 32 + g * 8);
#pragma unroll
    for (int i = 0; i < 4; ++i)
      afr[i] = *(const bf16x8*)(as + (wv * 64 + i * 16 + l15) * 32 + g * 8);
#pragma unroll
    for (int i = 0; i < 4; ++i)
#pragma unroll
      for (int j = 0; j < 4; ++j)
        acc[i][j] = __builtin_amdgcn_mfma_f32_16x16x32_bf16(afr[i], bfr[j], acc[i][j], 0, 0, 0);
  };

  gllA(0, 0);
  loadB(0);
  const int last = steps - 1;
  for (int t = 0; t < steps; ++t) {
    const int cur = t & 1;
    gllA(1 - cur, (t + 1 < last) ? t + 1 : last);
    storeB(cur);
    loadB((t + 1 < last) ? t + 1 : last);
    asm volatile("s_waitcnt vmcnt(12) lgkmcnt(0)" ::: "memory");
    __builtin_amdgcn_s_barrier();
    __builtin_amdgcn_sched_barrier(0);
    comp(cur);
    __builtin_amdgcn_sched_barrier(0);
    __builtin_amdgcn_s_barrier();
  }
  asm volatile("s_waitcnt vmcnt(0) lgkmcnt(0)" ::: "memory");
  __builtin_amdgcn_s_barrier();

  if (role == 0) {
    // bf16 partial in PANEL format: off = ((col/32)*256+m)*32 + col%32
    u16* C = parts + (size_t)bz * ((size_t)Kk * Nn);
    u16* sb = SH;                        // [256][72]
#pragma unroll
    for (int i = 0; i < 4; ++i)
#pragma unroll
      for (int j = 0; j < 4; ++j)
#pragma unroll
        for (int r = 0; r < 4; ++r)
          sb[(wv * 64 + i * 16 + g * 4 + r) * 72 + j * 16 + l15] = f2bf(acc[i][j][r]);
    __syncthreads();
    int c8 = tid & 7;
    size_t pb = (size_t)((col0 >> 5) + (c8 >> 2)) * 8192 + (c8 & 3) * 8;
#pragma unroll
    for (int e = 0; e < 8; ++e) {
      int m = (tid >> 3) + e * 32;
      uint4 v = *(const uint4*)(sb + m * 72 + c8 * 8);
      *(uint4*)(C + pb + (size_t)m * 32) = v;
    }
#pragma unroll
    for (int o = 32; o; o >>= 1) ss += __shfl_xor(ss, o);
    __syncthreads();
    if (lane == 0) sred[wv] = ss;
    __syncthreads();
    if (tid == 0) atomicAdd(sumsq, sred[0] + sred[1] + sred[2] + sred[3]);
  } else {
    float* Cz = (role == 1 ? fp_part + (size_t)bz * 131072
                           : ss_part + (size_t)bz * 65536);
    const int ldc = (role == 1 ? Dd : Kk);
    float* sf = (float*)SH;              // [128][68]
#pragma unroll
    for (int h = 0; h < 2; ++h) {
      __syncthreads();
      if ((wv >> 1) == h) {
#pragma unroll
        for (int i = 0; i < 4; ++i)
#pragma unroll
          for (int j = 0; j < 4; ++j)
#pragma unroll
            for (int r = 0; r < 4; ++r)
              sf[((wv & 1) * 64 + i * 16 + g * 4 + r) * 68 + j * 16 + l15] = acc[i][j][r];
      }
      __syncthreads();
#pragma unroll
      for (int e = 0; e < 8; ++e) {
        int idx2 = tid + e * 256;
        int m = idx2 >> 4, c4 = (idx2 & 15) * 4;
        float4 v = *(const float4*)(sf + m * 68 + c4);
        *(float4*)(Cz + (size_t)(h * 128 + m) * ldc + col0 + c4) = v;
      }
    }
  }
}

// ---------------- producers / small kernels ----------------
__launch_bounds__(256)
__global__ void cvtF_panel(const float* __restrict__ F, u16* __restrict__ pan,
                           float* __restrict__ cs, float* __restrict__ scal) {
  if (blockIdx.x == 2048) {
    int t = threadIdx.x;
    float4 z = {0.f, 0.f, 0.f, 0.f};
    if (t < 64) ((float4*)cs)[t] = z;
    else if (t < 66) ((float4*)scal)[t - 64] = z;   // scal[0..7] incl. counter
    return;
  }
  int idx = blockIdx.x * 256 + threadIdx.x;
  int m = idx >> 6, k0 = (idx & 63) * 8;
  float4 a = *(const float4*)(F + (size_t)m * Dd + k0);
  float4 b = *(const float4*)(F + (size_t)m * Dd + k0 + 4);
  ushort8_t h;
  h[0] = f2bf(a.x); h[1] = f2bf(a.y); h[2] = f2bf(a.z); h[3] = f2bf(a.w);
  h[4] = f2bf(b.x); h[5] = f2bf(b.y); h[6] = f2bf(b.z); h[7] = f2bf(b.w);
  int mb = m >> 8, mr = m & 255, p = k0 >> 5, c = k0 & 31;
  *(uint4*)(pan + ((size_t)(mb * 16 + p) * 256 + mr) * 32 + c) = __builtin_bit_cast(uint4, h);
}

__launch_bounds__(256)
__global__ void softmax_rows(float* __restrict__ io, const float* __restrict__ bias) {
  int wv = threadIdx.x >> 6, lane = threadIdx.x & 63;
  int n = blockIdx.x * 4 + wv;
  float4 b4 = ((const float4*)bias)[lane];
  float4 x = ((const float4*)(io + (size_t)n * Kk))[lane];
  x.x += b4.x; x.y += b4.y; x.z += b4.z; x.w += b4.w;
  float m = fmaxf(fmaxf(x.x, x.y), fmaxf(x.z, x.w));
#pragma unroll
  for (int o = 32; o; o >>= 1) m = fmaxf(m, __shfl_xor(m, o));
  float4 e = {__expf(x.x - m), __expf(x.y - m), __expf(x.z - m), __expf(x.w - m)};
  float s = e.x + e.y + e.z + e.w;
#pragma unroll
  for (int o = 32; o; o >>= 1) s += __shfl_xor(s, o);
  float inv = 1.f / s;
  e.x *= inv; e.y *= inv; e.z *= inv; e.w *= inv;
  ((float4*)(io + (size_t)n * Kk))[lane] = e;
}

__launch_bounds__(256)
__global__ void colsum_k(const float* __restrict__ a, float* __restrict__ cs) {
  __shared__ float4 red[4][64];
  int t = threadIdx.x, rg = t >> 6, c = t & 63;
  size_t n0 = (size_t)blockIdx.x * 128 + rg * 32;
  float4 s = {0.f, 0.f, 0.f, 0.f};
  for (int i = 0; i < 32; ++i) {
    float4 v = ((const float4*)(a + (n0 + i) * Kk))[c];
    s.x += v.x; s.y += v.y; s.z += v.z; s.w += v.w;
  }
  red[rg][c] = s;
  __syncthreads();
  if (rg == 0) {
    float4 a1 = red[1][c], a2 = red[2][c], a3 = red[3][c];
    s.x += a1.x + a2.x + a3.x; s.y += a1.y + a2.y + a3.y;
    s.z += a1.z + a2.z + a3.z; s.w += a1.w + a2.w + a3.w;
    atomicAdd(&cs[c * 4 + 0], s.x); atomicAdd(&cs[c * 4 + 1], s.y);
    atomicAdd(&cs[c * 4 + 2], s.z); atomicAdd(&cs[c * 4 + 3], s.w);
  }
}

// spT panel (inv folded) + entropy. block p: rows [32p,32p+32), thread = k.
__launch_bounds__(256)
__global__ void make_sp_pan(const float* __restrict__ a, const float* __restrict__ cs,
                            u16* __restrict__ pan, float* __restrict__ ent_sum) {
  __shared__ float sr[4];
  int p = blockIdx.x, k = threadIdx.x;
  float inv = 1.f / (cs[k] + 1e-8f);
  int n0 = p * 32;
  float ent = 0.f;
  ushort8_t h[4];
#pragma unroll
  for (int q = 0; q < 4; ++q) {
#pragma unroll
    for (int j = 0; j < 8; ++j) {
      float v = a[(size_t)(n0 + q * 8 + j) * Kk + k] * inv;
      h[q][j] = f2bf(v);
      ent -= v * __logf(v + 1e-15f);
    }
  }
  u16* dst = pan + ((size_t)p * 256 + k) * 32;
  *(uint4*)(dst + 0)  = __builtin_bit_cast(uint4, h[0]);
  *(uint4*)(dst + 8)  = __builtin_bit_cast(uint4, h[1]);
  *(uint4*)(dst + 16) = __builtin_bit_cast(uint4, h[2]);
  *(uint4*)(dst + 24) = __builtin_bit_cast(uint4, h[3]);
#pragma unroll
  for (int o = 32; o; o >>= 1) ent += __shfl_xor(ent, o);
  if ((k & 63) == 0) sr[k >> 6] = ent;
  __syncthreads();
  if (k == 0) atomicAdd(ent_sum, sr[0] + sr[1] + sr[2] + sr[3]);
}

// combine partials (+inv_cs column scaling for G5/G3) + last-block finalize.
// blocks 0-511: fpool (16 slices); 512-767: spTsp frob (16, x inv); 768-1023:
// apool (64 slices, x inv) + trace.
__launch_bounds__(256)
__global__ void combine3(const float* __restrict__ fp_part, const float* __restrict__ ss_part,
                         const float* __restrict__ ap_part, const float* __restrict__ cs,
                         float* __restrict__ fpool, float* __restrict__ apool,
                         float* __restrict__ scal,
                         float* __restrict__ olink, float* __restrict__ oent) {
  __shared__ float sr[4];
  __shared__ int lastS;
  int b = blockIdx.x, t = threadIdx.x;
  if (b < 512) {
    int i = b * 256 + t;
    float s = 0.f;
#pragma unroll
    for (int z = 0; z < 16; ++z) s += fp_part[z * 131072 + i];
    fpool[i] = s;
  } else if (b < 768) {
    int i = (b - 512) * 256 + t;
    float s = 0.f;
#pragma unroll
    for (int z = 0; z < 16; ++z) s += ss_part[z * 65536 + i];
    s *= 1.f / (cs[i & 255] + 1e-8f);
    float q = s * s;
#pragma unroll
    for (int o = 32; o; o >>= 1) q += __shfl_xor(q, o);
    if ((t & 63) == 0) sr[t >> 6] = q;
    __syncthreads();
    if (t == 0) atomicAdd(&scal[2], sr[0] + sr[1] + sr[2] + sr[3]);
  } else {
    int i = (b - 768) * 256 + t;
    float s = 0.f;
#pragma unroll
    for (int z = 0; z < 64; ++z) s += ap_part[z * 65536 + i];
    s *= 1.f / (cs[i & 255] + 1e-8f);
    apool[i] = s;
    if (i % 257 == 0) atomicAdd(&scal[3], s);
  }
  __threadfence();
  if (t == 0) {
    int* cnt = (int*)&scal[4];
    lastS = (atomicAdd(cnt, 1) == 1023);
  }
  __syncthreads();
  if (lastS && t == 0) {
    __threadfence();
    volatile float* sc = scal;
    float val = sc[0] - 2.f * sc[3] + sc[2];
    *olink = sqrtf(fmaxf(val, 0.f)) / ((float)Nn * (float)Nn);
    *oent  = sc[1] / (float)Nn;
  }
}

// ---------------- launch ----------------
extern "C" void kernel_launch(void* const* d_in, const int* in_sizes, int n_in,
                              void* d_out, int out_size, void* d_ws, size_t ws_size,
                              hipStream_t stream) {
  const float* F    = (const float*)d_in[0];
  const float* Adj  = (const float*)d_in[1];
  const float* W    = (const float*)d_in[2];
  const float* bias = (const float*)d_in[3];
  float* out = (float*)d_out;
  char* ws = (char*)d_ws;

  u16*  FbfPan  = (u16*)(ws + 0);            // 8 MB (dead after G1)
  u16*  parts   = (u16*)(ws + 0);            // 8 x 4 MB bf16 G2 panel-partials
  u16*  spTpan  = (u16*)(ws + 33554432);     // 4 MB
  float* fp_part = (float*)(ws + 37748736);  // 8 MB (16 x 131072)
  float* ss_part = (float*)(ws + 46137344);  // 4 MB (16 x 65536)
  float* ap_part = (float*)(ws + 50331648);  // 16 MB (64 x 65536)
  float* cs     = (float*)(ws + 67108864);   // 1 KB
  float* scal   = (float*)(ws + 67109888);   // [0]sumA2 [1]ent [2]frob [3]trace [4]cnt

  float* fpool  = out;
  float* assign = out + 131072;
  float* apool  = out + 2228224;
  float* olink  = out + 2293760;
  float* oent   = out + 2293761;

  cvtF_panel<<<2049, 256, 0, stream>>>(F, FbfPan, cs, scal);

  // G1: logits = F @ W -> assign, softmax in place
  gemm2<false, 2><<<dim3(4, 32, 1), 256, 0, stream>>>(
      FbfPan, 16, W, Kk, assign, Kk, Dd, 0, 0);
  softmax_rows<<<2048, 256, 0, stream>>>(assign, bias);
  colsum_k<<<64, 256, 0, stream>>>(assign, cs);
  make_sp_pan<<<256, 256, 0, stream>>>(assign, cs, spTpan, &scal[1]);

  // mega: G4 (fp_part) + G5 (ss_part raw) + G2 (P panel-partials + sumA2)
  gemm_mega<<<1216, 256, 0, stream>>>(spTpan, Adj, parts, &scal[0],
                                      F, fp_part, assign, ss_part);

  // G3: apool raw partials = [parts] @ assign-rows (Kin=65536, z=64)
  gemm2<true, 2><<<dim3(4, 1, 64), 256, 0, stream>>>(
      parts, 0, assign, Kk, ap_part, Kk, 1024, 65536, 1);

  combine3<<<1024, 256, 0, stream>>>(fp_part, ss_part, ap_part, cs, fpool, apool,
                                     scal, olink, oent);
}

// Round 13
// 264.070 us; speedup vs baseline: 1.1254x; 1.0117x over previous
//
#include <hip/hip_runtime.h>

// DiffPooling on MI355X (gfx950).
// outputs f32 concat: features_pooled (256x512), assignments (8192x256),
// adjacency_pooled (256x256), link_loss, ent_loss.
// link_loss: ||A - sp sp^T||_F^2 = sum(A^2) - 2*tr(adj_pooled) + ||sp^T sp||_F^2
//
// MFMA A-operands in "panel" format (stride-32 u16 rows, gll-linear):
//   offset_u16(p, m, k) = (p*256 + m)*32 + (k%32),  p = global_k/32
// Structure = R8 baseline (204.5 us): separate G4/G5/G2 dispatches (G2 exactly
// 1024 blocks = 4/CU, no tail), combine_P, G3 over Ppan. Lessons: mega>1024
// blocks creates a giant tail; G3-over-parts reads cross-XCD (no L2 locality);
// 2-deep B prefetch spills at OCC=4. Only delta vs R8: finalize folded into
// combine3 (last-block counter).

typedef unsigned short u16;
typedef __bf16 bf16x8 __attribute__((ext_vector_type(8)));
typedef float f32x4 __attribute__((ext_vector_type(4)));
typedef float float8_t __attribute__((ext_vector_type(8)));
typedef unsigned short ushort8_t __attribute__((ext_vector_type(8)));

#define Nn 8192
#define Dd 512
#define Kk 256

__device__ __forceinline__ u16 f2bf(float f) {
  unsigned int u = __builtin_bit_cast(unsigned int, f);
  u += 0x7FFFu + ((u >> 16) & 1u);   // RNE
  return (u16)(u >> 16);
}
__device__ __forceinline__ float bf2f(u16 h) {
  return __builtin_bit_cast(float, (unsigned int)h << 16);
}
__device__ __forceinline__ void gll16(const void* g, void* l) {
  __builtin_amdgcn_global_load_lds(
      (const __attribute__((address_space(1))) unsigned int*)g,
      (__attribute__((address_space(3))) unsigned int*)l, 16, 0, 0);
}

template <bool B> struct BRegSel { typedef float8_t T; };
template <> struct BRegSel<true> { typedef ushort8_t T; };

// ---------------- panel-A bf16 MFMA GEMM, counted-vmcnt pipeline ----------------
// C(256 x 64 per block) = Apanel @ B(row-major, ldb; f32->bf16 on the fly if !BF16B)
// 256 threads / 4 waves, wave tile 64x64, BK=32, double-buffered LDS, 40960 B.
// Per step t: gllA(other, t+1)[4] ; storeB(cur) [implicit wait drains B(t)+A(t)] ;
//             loadB(t+1)[8] ; s_waitcnt vmcnt(12) lgkmcnt(0) ; barrier ;
//             MFMA(cur) ; barrier.
// OUTKIND: 0 = f32 store via LDS at Cv + bz*zstride (G1 zstride=0, G4/G5/G3
//              z-partials), 1 = bf16 linear z-partial via LDS (G2).
template <bool BF16B, bool SUMSQ, int OUTKIND, int OCC>
__launch_bounds__(256, OCC)
__global__ void gemm2(const u16* __restrict__ Apan, int ppmb,
                      const void* __restrict__ Bv, int ldb,
                      void* __restrict__ Cv, int ldc,
                      int kchunk, size_t zstride,
                      float* __restrict__ sumsq, int swz) {
  __shared__ alignas(16) u16 SH[2 * 8192 + 2 * 2048];  // 40960 B exactly
  float* sred = (float*)&SH[20472];                    // last 16 B

  int bx = blockIdx.x, bz = blockIdx.z;
  if (swz) {  // XCD-chunked bijective remap (total % 8 == 0)
    int gx = gridDim.x, tot = gx * gridDim.z;
    int f = bx + gx * bz;
    int l = (f & 7) * (tot >> 3) + (f >> 3);
    bx = l % gx; bz = l / gx;
  }
  const int tid = threadIdx.x, wv = tid >> 6, lane = tid & 63;
  const int l15 = lane & 15, g = lane >> 4;
  const int col0 = bx * 64;
  const int row0 = blockIdx.y * 256;
  const int kbeg = bz * kchunk;
  const int steps = kchunk >> 5;
  const u16* pbase = Apan + (size_t)(blockIdx.y * ppmb + (kbeg >> 5)) * 8192;

  float ss = 0.f;
  typename BRegSel<BF16B>::T rb;

  auto loadB = [&](int t) {   // thread owns column (col0+lane), rows wv*8..+7
    const int kq = kbeg + t * 32 + wv * 8;
    if constexpr (BF16B) {
      const u16* p = (const u16*)Bv + (size_t)kq * ldb + col0 + lane;
#pragma unroll
      for (int i = 0; i < 8; ++i) rb[i] = p[(size_t)i * ldb];
    } else {
      const float* p = (const float*)Bv + (size_t)kq * ldb + col0 + lane;
#pragma unroll
      for (int i = 0; i < 8; ++i) rb[i] = p[(size_t)i * ldb];
    }
  };
  auto storeB = [&](int buf) {  // pack 8 k-elems of one col -> one b128
    ushort8_t h;
    if constexpr (BF16B) {
      h = rb;
    } else {
#pragma unroll
      for (int i = 0; i < 8; ++i) {
        h[i] = f2bf(rb[i]);
        if constexpr (SUMSQ) ss += rb[i] * rb[i];
      }
    }
    *(uint4*)&SH[16384 + buf * 2048 + lane * 32 + wv * 8] = __builtin_bit_cast(uint4, h);
  };
  auto gllA = [&](int buf, int t) {      // 16 KB panel tile -> LDS, linear, coalesced
    const char* gp = (const char*)(pbase + (size_t)t * 8192) + wv * 4096 + lane * 16;
    char* lp = (char*)&SH[buf * 8192] + wv * 4096;
#pragma unroll
    for (int r = 0; r < 4; ++r) gll16(gp + r * 1024, lp + r * 1024);
  };

  f32x4 acc[4][4];
#pragma unroll
  for (int i = 0; i < 4; ++i)
#pragma unroll
    for (int j = 0; j < 4; ++j) acc[i][j] = (f32x4){0.f, 0.f, 0.f, 0.f};

  auto comp = [&](int buf) {
    const u16* as = &SH[buf * 8192];
    const u16* bs = &SH[16384 + buf * 2048];
    bf16x8 afr[4], bfr[4];
#pragma unroll
    for (int j = 0; j < 4; ++j)
      bfr[j] = *(const bf16x8*)(bs + (j * 16 + l15) * 32 + g * 8);
#pragma unroll
    for (int i = 0; i < 4; ++i)
      afr[i] = *(const bf16x8*)(as + (wv * 64 + i * 16 + l15) * 32 + g * 8);
#pragma unroll
    for (int i = 0; i < 4; ++i)
#pragma unroll
      for (int j = 0; j < 4; ++j)
        acc[i][j] = __builtin_amdgcn_mfma_f32_16x16x32_bf16(afr[i], bfr[j], acc[i][j], 0, 0, 0);
  };

  // prologue: A(0), B(0) in flight
  gllA(0, 0);
  loadB(0);
  const int last = steps - 1;

  for (int t = 0; t < steps; ++t) {
    const int cur = t & 1;
    gllA(1 - cur, (t + 1 < last) ? t + 1 : last);
    storeB(cur);                          // implicit wait: drains A(t)+B(t)
    loadB((t + 1 < last) ? t + 1 : last);
    asm volatile("s_waitcnt vmcnt(12) lgkmcnt(0)" ::: "memory");
    __builtin_amdgcn_s_barrier();
    __builtin_amdgcn_sched_barrier(0);
    comp(cur);
    __builtin_amdgcn_sched_barrier(0);
    __builtin_amdgcn_s_barrier();
  }
  // full drain before LDS reuse in epilogues
  asm volatile("s_waitcnt vmcnt(0) lgkmcnt(0)" ::: "memory");
  __builtin_amdgcn_s_barrier();

  // epilogues (C/D layout m89-verified: col = j*16+l15, row = wv*64+i*16+g*4+r)
  if constexpr (OUTKIND == 0) {          // f32 via LDS, two 128-row halves
    float* Cz = (float*)Cv + (size_t)bz * zstride;
    float* sf = (float*)SH;              // [128][68] f32 (34816 B)
#pragma unroll
    for (int h = 0; h < 2; ++h) {
      __syncthreads();
      if ((wv >> 1) == h) {
#pragma unroll
        for (int i = 0; i < 4; ++i)
#pragma unroll
          for (int j = 0; j < 4; ++j)
#pragma unroll
            for (int r = 0; r < 4; ++r)
              sf[((wv & 1) * 64 + i * 16 + g * 4 + r) * 68 + j * 16 + l15] = acc[i][j][r];
      }
      __syncthreads();
#pragma unroll
      for (int e = 0; e < 8; ++e) {     // 2048 float4s = full 128x64 tile
        int idx2 = tid + e * 256;
        int m = idx2 >> 4, c4 = (idx2 & 15) * 4;
        float4 v = *(const float4*)(sf + m * 68 + c4);
        *(float4*)(Cz + (size_t)(row0 + h * 128 + m) * ldc + col0 + c4) = v;
      }
    }
  } else {                               // bf16 linear z-partial via LDS (G2)
    u16* C = (u16*)Cv + (size_t)bz * zstride;
    u16* sb = SH;                        // [256][72] u16 (36864 B)
#pragma unroll
    for (int i = 0; i < 4; ++i)
#pragma unroll
      for (int j = 0; j < 4; ++j)
#pragma unroll
        for (int r = 0; r < 4; ++r)
          sb[(wv * 64 + i * 16 + g * 4 + r) * 72 + j * 16 + l15] = f2bf(acc[i][j][r]);
    __syncthreads();
#pragma unroll
    for (int e = 0; e < 8; ++e) {
      int m = (tid >> 3) + e * 32;
      uint4 v = *(const uint4*)(sb + m * 72 + (tid & 7) * 8);
      *(uint4*)(C + (size_t)m * ldc + col0 + (tid & 7) * 8) = v;
    }
  }

  if constexpr (SUMSQ) {
#pragma unroll
    for (int o = 32; o; o >>= 1) ss += __shfl_xor(ss, o);
    __syncthreads();
    if (lane == 0) sred[wv] = ss;
    __syncthreads();
    if (tid == 0) atomicAdd(sumsq, sred[0] + sred[1] + sred[2] + sred[3]);
  }
}

// ---------------- producers / small kernels ----------------
// F f32 -> panel bf16; extra last block zeroes cs + scal (incl. finalize counter)
__launch_bounds__(256)
__global__ void cvtF_panel(const float* __restrict__ F, u16* __restrict__ pan,
                           float* __restrict__ cs, float* __restrict__ scal) {
  if (blockIdx.x == 2048) {
    int t = threadIdx.x;
    float4 z = {0.f, 0.f, 0.f, 0.f};
    if (t < 64) ((float4*)cs)[t] = z;
    else if (t < 66) ((float4*)scal)[t - 64] = z;   // scal[0..7] incl. counter
    return;
  }
  int idx = blockIdx.x * 256 + threadIdx.x;      // 524288 groups of 8
  int m = idx >> 6, k0 = (idx & 63) * 8;
  float4 a = *(const float4*)(F + (size_t)m * Dd + k0);
  float4 b = *(const float4*)(F + (size_t)m * Dd + k0 + 4);
  ushort8_t h;
  h[0] = f2bf(a.x); h[1] = f2bf(a.y); h[2] = f2bf(a.z); h[3] = f2bf(a.w);
  h[4] = f2bf(b.x); h[5] = f2bf(b.y); h[6] = f2bf(b.z); h[7] = f2bf(b.w);
  int mb = m >> 8, mr = m & 255, p = k0 >> 5, c = k0 & 31;
  *(uint4*)(pan + ((size_t)(mb * 16 + p) * 256 + mr) * 32 + c) = __builtin_bit_cast(uint4, h);
}

// wave-per-row softmax: block = 4 waves = 4 rows; lane holds 4 cols (float4).
__launch_bounds__(256)
__global__ void softmax_rows(float* __restrict__ io, const float* __restrict__ bias) {
  int wv = threadIdx.x >> 6, lane = threadIdx.x & 63;
  int n = blockIdx.x * 4 + wv;
  float4 b4 = ((const float4*)bias)[lane];
  float4 x = ((const float4*)(io + (size_t)n * Kk))[lane];
  x.x += b4.x; x.y += b4.y; x.z += b4.z; x.w += b4.w;
  float m = fmaxf(fmaxf(x.x, x.y), fmaxf(x.z, x.w));
#pragma unroll
  for (int o = 32; o; o >>= 1) m = fmaxf(m, __shfl_xor(m, o));
  float4 e = {__expf(x.x - m), __expf(x.y - m), __expf(x.z - m), __expf(x.w - m)};
  float s = e.x + e.y + e.z + e.w;
#pragma unroll
  for (int o = 32; o; o >>= 1) s += __shfl_xor(s, o);
  float inv = 1.f / s;
  e.x *= inv; e.y *= inv; e.z *= inv; e.w *= inv;
  ((float4*)(io + (size_t)n * Kk))[lane] = e;
}

// colsum: 64 blocks x 128 rows; thread (rg = t>>6, c4 = (t&63)*4); float4.
__launch_bounds__(256)
__global__ void colsum_k(const float* __restrict__ a, float* __restrict__ cs) {
  __shared__ float4 red[4][64];
  int t = threadIdx.x, rg = t >> 6, c = t & 63;
  size_t n0 = (size_t)blockIdx.x * 128 + rg * 32;
  float4 s = {0.f, 0.f, 0.f, 0.f};
  for (int i = 0; i < 32; ++i) {
    float4 v = ((const float4*)(a + (n0 + i) * Kk))[c];
    s.x += v.x; s.y += v.y; s.z += v.z; s.w += v.w;
  }
  red[rg][c] = s;
  __syncthreads();
  if (rg == 0) {
    float4 a1 = red[1][c], a2 = red[2][c], a3 = red[3][c];
    s.x += a1.x + a2.x + a3.x; s.y += a1.y + a2.y + a3.y;
    s.z += a1.z + a2.z + a3.z; s.w += a1.w + a2.w + a3.w;
    atomicAdd(&cs[c * 4 + 0], s.x); atomicAdd(&cs[c * 4 + 1], s.y);
    atomicAdd(&cs[c * 4 + 2], s.z); atomicAdd(&cs[c * 4 + 3], s.w);
  }
}

// fused: sp (bf16 row-major) + spT panel + entropy. block p: rows [32p,32p+32).
__launch_bounds__(256)
__global__ void make_sp_all(const float* __restrict__ a, const float* __restrict__ cs,
                            u16* __restrict__ spb, u16* __restrict__ pan,
                            float* __restrict__ ent_sum) {
  __shared__ float sr[4];
  int p = blockIdx.x, k = threadIdx.x;
  float inv = 1.f / (cs[k] + 1e-8f);
  int n0 = p * 32;
  float ent = 0.f;
  ushort8_t h[4];
#pragma unroll
  for (int q = 0; q < 4; ++q) {
#pragma unroll
    for (int j = 0; j < 8; ++j) {
      float v = a[(size_t)(n0 + q * 8 + j) * Kk + k] * inv;
      u16 hb = f2bf(v);
      h[q][j] = hb;
      ent -= v * __logf(v + 1e-15f);
      spb[(size_t)(n0 + q * 8 + j) * Kk + k] = hb;
    }
  }
  u16* dst = pan + ((size_t)p * 256 + k) * 32;
  *(uint4*)(dst + 0)  = __builtin_bit_cast(uint4, h[0]);
  *(uint4*)(dst + 8)  = __builtin_bit_cast(uint4, h[1]);
  *(uint4*)(dst + 16) = __builtin_bit_cast(uint4, h[2]);
  *(uint4*)(dst + 24) = __builtin_bit_cast(uint4, h[3]);
#pragma unroll
  for (int o = 32; o; o >>= 1) ent += __shfl_xor(ent, o);
  if ((k & 63) == 0) sr[k >> 6] = ent;
  __syncthreads();
  if (k == 0) atomicAdd(ent_sum, sr[0] + sr[1] + sr[2] + sr[3]);
}

// sum 8 bf16 partials -> P panel (stride-32)
__launch_bounds__(256)
__global__ void combine_P(const u16* __restrict__ part, u16* __restrict__ pan) {
  int idx = blockIdx.x * 256 + threadIdx.x;      // 262144
  int m = idx >> 10, kk8 = idx & 1023;
  size_t off = (size_t)m * Nn + kk8 * 8;
  float8_t s = {0.f, 0.f, 0.f, 0.f, 0.f, 0.f, 0.f, 0.f};
#pragma unroll
  for (int z = 0; z < 8; ++z) {
    ushort8_t v = __builtin_bit_cast(ushort8_t,
        *(const uint4*)(part + (size_t)z * Kk * Nn + off));
#pragma unroll
    for (int j = 0; j < 8; ++j) s[j] += bf2f(v[j]);
  }
  ushort8_t h;
#pragma unroll
  for (int j = 0; j < 8; ++j) h[j] = f2bf(s[j]);
  int p = kk8 >> 2, c = (kk8 & 3) * 8;
  *(uint4*)(pan + ((size_t)p * 256 + m) * 32 + c) = __builtin_bit_cast(uint4, h);
}

// combine partials + last-block finalize.
// blocks 0-511: fpool (16); 512-767: frob(spTsp) (16); 768-1023: apool (16) + trace.
__launch_bounds__(256)
__global__ void combine3(const float* __restrict__ fp_part, const float* __restrict__ ss_part,
                         const float* __restrict__ ap_part,
                         float* __restrict__ fpool, float* __restrict__ apool,
                         float* __restrict__ scal,
                         float* __restrict__ olink, float* __restrict__ oent) {
  __shared__ float sr[4];
  __shared__ int lastS;
  int b = blockIdx.x, t = threadIdx.x;
  if (b < 512) {
    int i = b * 256 + t;
    float s = 0.f;
#pragma unroll
    for (int z = 0; z < 16; ++z) s += fp_part[z * 131072 + i];
    fpool[i] = s;
  } else if (b < 768) {
    int i = (b - 512) * 256 + t;
    float s = 0.f;
#pragma unroll
    for (int z = 0; z < 16; ++z) s += ss_part[z * 65536 + i];
    float q = s * s;
#pragma unroll
    for (int o = 32; o; o >>= 1) q += __shfl_xor(q, o);
    if ((t & 63) == 0) sr[t >> 6] = q;
    __syncthreads();
    if (t == 0) atomicAdd(&scal[2], sr[0] + sr[1] + sr[2] + sr[3]);
  } else {
    int i = (b - 768) * 256 + t;
    float s = 0.f;
#pragma unroll
    for (int z = 0; z < 16; ++z) s += ap_part[z * 65536 + i];
    apool[i] = s;
    if (i % 257 == 0) atomicAdd(&scal[3], s);
  }
  // last-block finalize (counter scal[4], zeroed each launch by cvtF_panel)
  __threadfence();
  if (t == 0) {
    int* cnt = (int*)&scal[4];
    lastS = (atomicAdd(cnt, 1) == 1023);
  }
  __syncthreads();
  if (lastS && t == 0) {
    __threadfence();
    volatile float* sc = scal;
    float val = sc[0] - 2.f * sc[3] + sc[2];
    *olink = sqrtf(fmaxf(val, 0.f)) / ((float)Nn * (float)Nn);
    *oent  = sc[1] / (float)Nn;
  }
}

// ---------------- launch ----------------
extern "C" void kernel_launch(void* const* d_in, const int* in_sizes, int n_in,
                              void* d_out, int out_size, void* d_ws, size_t ws_size,
                              hipStream_t stream) {
  const float* F    = (const float*)d_in[0];
  const float* Adj  = (const float*)d_in[1];
  const float* W    = (const float*)d_in[2];
  const float* bias = (const float*)d_in[3];
  float* out = (float*)d_out;
  char* ws = (char*)d_ws;

  u16*  FbfPan  = (u16*)(ws + 0);           // 8 MB (dead after G1; overlaid by parts)
  u16*  parts   = (u16*)(ws + 0);           // 8 x 4 MB bf16 G2 linear partials
  u16*  spb     = (u16*)(ws + 33554432);    // 4 MB
  u16*  spTpan  = (u16*)(ws + 37748736);    // 4 MB
  u16*  Ppan    = (u16*)(ws + 41943040);    // 4 MB
  float* fp_part = (float*)(ws + 46137344); // 8 MB (16 x 131072 f32)
  float* ss_part = (float*)(ws + 54525952); // 4 MB (16 x 65536 f32)
  float* ap_part = (float*)(ws + 58720256); // 4 MB (16 x 65536 f32)
  float* cs     = (float*)(ws + 62914560);  // 1 KB
  float* scal   = (float*)(ws + 62915584);  // [0]sumA2 [1]ent [2]frob [3]trace [4]cnt

  float* fpool  = out;
  float* assign = out + 131072;
  float* apool  = out + 2228224;
  float* olink  = out + 2293760;
  float* oent   = out + 2293761;

  cvtF_panel<<<2049, 256, 0, stream>>>(F, FbfPan, cs, scal);

  // G1: logits = F @ W (W f32 converted on the fly) -> assign, softmax in place
  gemm2<false, false, 0, 2><<<dim3(4, 32, 1), 256, 0, stream>>>(
      FbfPan, 16, W, Kk, assign, Kk, Dd, 0, nullptr, 0);
  softmax_rows<<<2048, 256, 0, stream>>>(assign, bias);
  colsum_k<<<64, 256, 0, stream>>>(assign, cs);
  make_sp_all<<<256, 256, 0, stream>>>(assign, cs, spb, spTpan, &scal[1]);

  // G4: features_pooled partials = spT @ F (16 z-chunks, plain f32 stores)
  gemm2<false, false, 0, 2><<<dim3(8, 1, 16), 256, 0, stream>>>(
      spTpan, 256, F, Dd, fp_part, Dd, Nn / 16, 131072, nullptr, 1);
  // G5: spTsp partials = spT @ sp
  gemm2<true, false, 0, 2><<<dim3(4, 1, 16), 256, 0, stream>>>(
      spTpan, 256, spb, Kk, ss_part, Kk, Nn / 16, 65536, nullptr, 1);
  // G2: P = spT @ A: 8 bf16 partials + fused sum(A^2), XCD-chunked, 4 blk/CU
  gemm2<false, true, 1, 4><<<dim3(128, 1, 8), 256, 0, stream>>>(
      spTpan, 256, Adj, Nn, parts, Nn, Nn / 8, (size_t)Kk * Nn, &scal[0], 1);
  combine_P<<<1024, 256, 0, stream>>>(parts, Ppan);
  // G3: adjacency_pooled partials = P @ sp
  gemm2<true, false, 0, 2><<<dim3(4, 1, 16), 256, 0, stream>>>(
      Ppan, 256, spb, Kk, ap_part, Kk, Nn / 16, 65536, nullptr, 1);

  combine3<<<1024, 256, 0, stream>>>(fp_part, ss_part, ap_part, fpool, apool,
                                     scal, olink, oent);
}

// Round 14
// 200.732 us; speedup vs baseline: 1.4805x; 1.3155x over previous
//
#include <hip/hip_runtime.h>

// DiffPooling on MI355X (gfx950).
// outputs f32 concat: features_pooled (256x512), assignments (8192x256),
// adjacency_pooled (256x256), link_loss, ent_loss.
// link_loss: ||A - sp sp^T||_F^2 = sum(A^2) - 2*tr(adj_pooled) + ||sp^T sp||_F^2
//
// MFMA A-operands in "panel" format (stride-32 u16 rows, gll-linear):
//   offset_u16(p, m, k) = (p*256 + m)*32 + (k%32),  p = global_k/32
// R14 = EXACT resubmission of R8 (204.5 us) as an A/B control: R10-R13 all
// carry combine3's last-block __threadfence (suspected L2-writeback cost,
// +60 us) vs R8's separate finalize_k. This round decides threadfence-
// regression vs session-variance.

typedef unsigned short u16;
typedef __bf16 bf16x8 __attribute__((ext_vector_type(8)));
typedef float f32x4 __attribute__((ext_vector_type(4)));
typedef float float8_t __attribute__((ext_vector_type(8)));
typedef unsigned short ushort8_t __attribute__((ext_vector_type(8)));

#define Nn 8192
#define Dd 512
#define Kk 256

__device__ __forceinline__ u16 f2bf(float f) {
  unsigned int u = __builtin_bit_cast(unsigned int, f);
  u += 0x7FFFu + ((u >> 16) & 1u);   // RNE
  return (u16)(u >> 16);
}
__device__ __forceinline__ float bf2f(u16 h) {
  return __builtin_bit_cast(float, (unsigned int)h << 16);
}
__device__ __forceinline__ void gll16(const void* g, void* l) {
  __builtin_amdgcn_global_load_lds(
      (const __attribute__((address_space(1))) unsigned int*)g,
      (__attribute__((address_space(3))) unsigned int*)l, 16, 0, 0);
}

template <bool B> struct BRegSel { typedef float8_t T; };
template <> struct BRegSel<true> { typedef ushort8_t T; };

// ---------------- panel-A bf16 MFMA GEMM, counted-vmcnt pipeline ----------------
// C(256 x 64 per block) = Apanel @ B(row-major, ldb; f32->bf16 on the fly if !BF16B)
// 256 threads / 4 waves, wave tile 64x64, BK=32, double-buffered LDS, 40960 B.
// Per step t: gllA(other, t+1)[4] ; storeB(cur) [implicit wait drains B(t)+A(t)] ;
//             loadB(t+1)[8] ; s_waitcnt vmcnt(12) lgkmcnt(0) ; barrier ;
//             MFMA(cur) ; barrier.
// OUTKIND: 0 = f32 store via LDS at Cv + bz*zstride (G1 zstride=0, G4/G5/G3
//              z-partials), 1 = bf16 z-partial via LDS (G2).
template <bool BF16B, bool SUMSQ, int OUTKIND, int OCC>
__launch_bounds__(256, OCC)
__global__ void gemm2(const u16* __restrict__ Apan, int ppmb,
                      const void* __restrict__ Bv, int ldb,
                      void* __restrict__ Cv, int ldc,
                      int kchunk, size_t zstride,
                      float* __restrict__ sumsq, int swz) {
  __shared__ alignas(16) u16 SH[2 * 8192 + 2 * 2048];  // 40960 B exactly
  float* sred = (float*)&SH[20472];                    // last 16 B of SH

  int bx = blockIdx.x, bz = blockIdx.z;
  if (swz) {  // XCD-chunked bijective remap (total % 8 == 0)
    int gx = gridDim.x, tot = gx * gridDim.z;
    int f = bx + gx * bz;
    int l = (f & 7) * (tot >> 3) + (f >> 3);
    bx = l % gx; bz = l / gx;
  }
  const int tid = threadIdx.x, wv = tid >> 6, lane = tid & 63;
  const int l15 = lane & 15, g = lane >> 4;
  const int col0 = bx * 64;
  const int row0 = blockIdx.y * 256;
  const int kbeg = bz * kchunk;
  const int steps = kchunk >> 5;
  const u16* pbase = Apan + (size_t)(blockIdx.y * ppmb + (kbeg >> 5)) * 8192;

  float ss = 0.f;
  typename BRegSel<BF16B>::T rb;

  auto loadB = [&](int t) {   // thread owns column (col0+lane), rows wv*8..+7
    const int kq = kbeg + t * 32 + wv * 8;
    if constexpr (BF16B) {
      const u16* p = (const u16*)Bv + (size_t)kq * ldb + col0 + lane;
#pragma unroll
      for (int i = 0; i < 8; ++i) rb[i] = p[(size_t)i * ldb];
    } else {
      const float* p = (const float*)Bv + (size_t)kq * ldb + col0 + lane;
#pragma unroll
      for (int i = 0; i < 8; ++i) rb[i] = p[(size_t)i * ldb];
    }
  };
  auto storeB = [&](int buf) {  // pack 8 k-elems of one col -> one b128
    ushort8_t h;
    if constexpr (BF16B) {
      h = rb;
    } else {
#pragma unroll
      for (int i = 0; i < 8; ++i) {
        h[i] = f2bf(rb[i]);
        if constexpr (SUMSQ) ss += rb[i] * rb[i];
      }
    }
    *(uint4*)&SH[16384 + buf * 2048 + lane * 32 + wv * 8] = __builtin_bit_cast(uint4, h);
  };
  auto gllA = [&](int buf, int t) {      // 16 KB panel tile -> LDS, linear, coalesced
    const char* gp = (const char*)(pbase + (size_t)t * 8192) + wv * 4096 + lane * 16;
    char* lp = (char*)&SH[buf * 8192] + wv * 4096;
#pragma unroll
    for (int r = 0; r < 4; ++r) gll16(gp + r * 1024, lp + r * 1024);
  };

  f32x4 acc[4][4];
#pragma unroll
  for (int i = 0; i < 4; ++i)
#pragma unroll
    for (int j = 0; j < 4; ++j) acc[i][j] = (f32x4){0.f, 0.f, 0.f, 0.f};

  auto comp = [&](int buf) {
    const u16* as = &SH[buf * 8192];
    const u16* bs = &SH[16384 + buf * 2048];
    bf16x8 afr[4], bfr[4];
#pragma unroll
    for (int j = 0; j < 4; ++j)
      bfr[j] = *(const bf16x8*)(bs + (j * 16 + l15) * 32 + g * 8);
#pragma unroll
    for (int i = 0; i < 4; ++i)
      afr[i] = *(const bf16x8*)(as + (wv * 64 + i * 16 + l15) * 32 + g * 8);
#pragma unroll
    for (int i = 0; i < 4; ++i)
#pragma unroll
      for (int j = 0; j < 4; ++j)
        acc[i][j] = __builtin_amdgcn_mfma_f32_16x16x32_bf16(afr[i], bfr[j], acc[i][j], 0, 0, 0);
  };

  // prologue: A(0), B(0) in flight
  gllA(0, 0);
  loadB(0);
  const int last = steps - 1;

  for (int t = 0; t < steps; ++t) {
    const int cur = t & 1;
    gllA(1 - cur, (t + 1 < last) ? t + 1 : last);
    storeB(cur);                          // implicit wait: drains A(t)+B(t)
    loadB((t + 1 < last) ? t + 1 : last);
    asm volatile("s_waitcnt vmcnt(12) lgkmcnt(0)" ::: "memory");
    __builtin_amdgcn_s_barrier();
    __builtin_amdgcn_sched_barrier(0);
    comp(cur);
    __builtin_amdgcn_sched_barrier(0);
    __builtin_amdgcn_s_barrier();
  }
  // full drain before LDS reuse in epilogues
  asm volatile("s_waitcnt vmcnt(0) lgkmcnt(0)" ::: "memory");
  __builtin_amdgcn_s_barrier();

  // epilogues (C/D layout m89-verified: col = j*16+l15, row = wv*64+i*16+g*4+r)
  if constexpr (OUTKIND == 0) {          // f32 via LDS, two 128-row halves
    float* Cz = (float*)Cv + (size_t)bz * zstride;
    float* sf = (float*)SH;              // [128][68] f32 (34816 B)
#pragma unroll
    for (int h = 0; h < 2; ++h) {
      __syncthreads();
      if ((wv >> 1) == h) {
#pragma unroll
        for (int i = 0; i < 4; ++i)
#pragma unroll
          for (int j = 0; j < 4; ++j)
#pragma unroll
            for (int r = 0; r < 4; ++r)
              sf[((wv & 1) * 64 + i * 16 + g * 4 + r) * 68 + j * 16 + l15] = acc[i][j][r];
      }
      __syncthreads();
#pragma unroll
      for (int e = 0; e < 8; ++e) {     // 2048 float4s = full 128x64 tile
        int idx2 = tid + e * 256;
        int m = idx2 >> 4, c4 = (idx2 & 15) * 4;
        float4 v = *(const float4*)(sf + m * 68 + c4);
        *(float4*)(Cz + (size_t)(row0 + h * 128 + m) * ldc + col0 + c4) = v;
      }
    }
  } else {                               // bf16 z-partial via LDS (G2)
    u16* C = (u16*)Cv + (size_t)bz * zstride;
    u16* sb = SH;                        // [256][72] u16 (36864 B)
#pragma unroll
    for (int i = 0; i < 4; ++i)
#pragma unroll
      for (int j = 0; j < 4; ++j)
#pragma unroll
        for (int r = 0; r < 4; ++r)
          sb[(wv * 64 + i * 16 + g * 4 + r) * 72 + j * 16 + l15] = f2bf(acc[i][j][r]);
    __syncthreads();
#pragma unroll
    for (int e = 0; e < 8; ++e) {
      int m = (tid >> 3) + e * 32;
      uint4 v = *(const uint4*)(sb + m * 72 + (tid & 7) * 8);
      *(uint4*)(C + (size_t)m * ldc + col0 + (tid & 7) * 8) = v;
    }
  }

  if constexpr (SUMSQ) {
#pragma unroll
    for (int o = 32; o; o >>= 1) ss += __shfl_xor(ss, o);
    __syncthreads();
    if (lane == 0) sred[wv] = ss;
    __syncthreads();
    if (tid == 0) atomicAdd(sumsq, sred[0] + sred[1] + sred[2] + sred[3]);
  }
}

// ---------------- producers / small kernels ----------------
// F f32 -> panel bf16; extra last block zeroes cs + scal
__launch_bounds__(256)
__global__ void cvtF_panel(const float* __restrict__ F, u16* __restrict__ pan,
                           float* __restrict__ cs, float* __restrict__ scal) {
  if (blockIdx.x == 2048) {
    int t = threadIdx.x;
    float4 z = {0.f, 0.f, 0.f, 0.f};
    if (t < 64) ((float4*)cs)[t] = z;
    else if (t == 64) ((float4*)scal)[0] = z;   // scal[0..3]
    return;
  }
  int idx = blockIdx.x * 256 + threadIdx.x;      // 524288 groups of 8
  int m = idx >> 6, k0 = (idx & 63) * 8;
  float4 a = *(const float4*)(F + (size_t)m * Dd + k0);
  float4 b = *(const float4*)(F + (size_t)m * Dd + k0 + 4);
  ushort8_t h;
  h[0] = f2bf(a.x); h[1] = f2bf(a.y); h[2] = f2bf(a.z); h[3] = f2bf(a.w);
  h[4] = f2bf(b.x); h[5] = f2bf(b.y); h[6] = f2bf(b.z); h[7] = f2bf(b.w);
  int mb = m >> 8, mr = m & 255, p = k0 >> 5, c = k0 & 31;
  *(uint4*)(pan + ((size_t)(mb * 16 + p) * 256 + mr) * 32 + c) = __builtin_bit_cast(uint4, h);
}

// wave-per-row softmax: block = 4 waves = 4 rows; lane holds 4 cols (float4).
__launch_bounds__(256)
__global__ void softmax_rows(float* __restrict__ io, const float* __restrict__ bias) {
  int wv = threadIdx.x >> 6, lane = threadIdx.x & 63;
  int n = blockIdx.x * 4 + wv;
  float4 b4 = ((const float4*)bias)[lane];
  float4 x = ((const float4*)(io + (size_t)n * Kk))[lane];
  x.x += b4.x; x.y += b4.y; x.z += b4.z; x.w += b4.w;
  float m = fmaxf(fmaxf(x.x, x.y), fmaxf(x.z, x.w));
#pragma unroll
  for (int o = 32; o; o >>= 1) m = fmaxf(m, __shfl_xor(m, o));
  float4 e = {__expf(x.x - m), __expf(x.y - m), __expf(x.z - m), __expf(x.w - m)};
  float s = e.x + e.y + e.z + e.w;
#pragma unroll
  for (int o = 32; o; o >>= 1) s += __shfl_xor(s, o);
  float inv = 1.f / s;
  e.x *= inv; e.y *= inv; e.z *= inv; e.w *= inv;
  ((float4*)(io + (size_t)n * Kk))[lane] = e;
}

// colsum: 64 blocks x 128 rows; thread (rg = t>>6, c4 = (t&63)*4); float4.
__launch_bounds__(256)
__global__ void colsum_k(const float* __restrict__ a, float* __restrict__ cs) {
  __shared__ float4 red[4][64];
  int t = threadIdx.x, rg = t >> 6, c = t & 63;
  size_t n0 = (size_t)blockIdx.x * 128 + rg * 32;
  float4 s = {0.f, 0.f, 0.f, 0.f};
  for (int i = 0; i < 32; ++i) {
    float4 v = ((const float4*)(a + (n0 + i) * Kk))[c];
    s.x += v.x; s.y += v.y; s.z += v.z; s.w += v.w;
  }
  red[rg][c] = s;
  __syncthreads();
  if (rg == 0) {
    float4 a1 = red[1][c], a2 = red[2][c], a3 = red[3][c];
    s.x += a1.x + a2.x + a3.x; s.y += a1.y + a2.y + a3.y;
    s.z += a1.z + a2.z + a3.z; s.w += a1.w + a2.w + a3.w;
    atomicAdd(&cs[c * 4 + 0], s.x); atomicAdd(&cs[c * 4 + 1], s.y);
    atomicAdd(&cs[c * 4 + 2], s.z); atomicAdd(&cs[c * 4 + 3], s.w);
  }
}

// fused: sp (bf16 row-major) + spT panel + entropy. block p: rows [32p,32p+32).
__launch_bounds__(256)
__global__ void make_sp_all(const float* __restrict__ a, const float* __restrict__ cs,
                            u16* __restrict__ spb, u16* __restrict__ pan,
                            float* __restrict__ ent_sum) {
  __shared__ float sr[4];
  int p = blockIdx.x, k = threadIdx.x;
  float inv = 1.f / (cs[k] + 1e-8f);
  int n0 = p * 32;
  float ent = 0.f;
  ushort8_t h[4];
#pragma unroll
  for (int q = 0; q < 4; ++q) {
#pragma unroll
    for (int j = 0; j < 8; ++j) {
      float v = a[(size_t)(n0 + q * 8 + j) * Kk + k] * inv;
      u16 hb = f2bf(v);
      h[q][j] = hb;
      ent -= v * __logf(v + 1e-15f);
      spb[(size_t)(n0 + q * 8 + j) * Kk + k] = hb;
    }
  }
  u16* dst = pan + ((size_t)p * 256 + k) * 32;
  *(uint4*)(dst + 0)  = __builtin_bit_cast(uint4, h[0]);
  *(uint4*)(dst + 8)  = __builtin_bit_cast(uint4, h[1]);
  *(uint4*)(dst + 16) = __builtin_bit_cast(uint4, h[2]);
  *(uint4*)(dst + 24) = __builtin_bit_cast(uint4, h[3]);
#pragma unroll
  for (int o = 32; o; o >>= 1) ent += __shfl_xor(ent, o);
  if ((k & 63) == 0) sr[k >> 6] = ent;
  __syncthreads();
  if (k == 0) atomicAdd(ent_sum, sr[0] + sr[1] + sr[2] + sr[3]);
}

// sum 8 bf16 partials -> P panel (stride-32)
__launch_bounds__(256)
__global__ void combine_P(const u16* __restrict__ part, u16* __restrict__ pan) {
  int idx = blockIdx.x * 256 + threadIdx.x;      // 262144
  int m = idx >> 10, kk8 = idx & 1023;
  size_t off = (size_t)m * Nn + kk8 * 8;
  float8_t s = {0.f, 0.f, 0.f, 0.f, 0.f, 0.f, 0.f, 0.f};
#pragma unroll
  for (int z = 0; z < 8; ++z) {
    ushort8_t v = __builtin_bit_cast(ushort8_t,
        *(const uint4*)(part + (size_t)z * Kk * Nn + off));
#pragma unroll
    for (int j = 0; j < 8; ++j) s[j] += bf2f(v[j]);
  }
  ushort8_t h;
#pragma unroll
  for (int j = 0; j < 8; ++j) h[j] = f2bf(s[j]);
  int p = kk8 >> 2, c = (kk8 & 3) * 8;
  *(uint4*)(pan + ((size_t)p * 256 + m) * 32 + c) = __builtin_bit_cast(uint4, h);
}

// sum 16 f32 z-partials: blocks 0-511 fpool; 512-767 spTsp->frob into scal[2];
// 768-1023 apool (+trace into scal[3]).
__launch_bounds__(256)
__global__ void combine3(const float* __restrict__ fp_part, const float* __restrict__ ss_part,
                         const float* __restrict__ ap_part,
                         float* __restrict__ fpool, float* __restrict__ apool,
                         float* __restrict__ scal) {
  __shared__ float sr[4];
  int b = blockIdx.x, t = threadIdx.x;
  if (b < 512) {
    int i = b * 256 + t;
    float s = 0.f;
#pragma unroll
    for (int z = 0; z < 16; ++z) s += fp_part[z * 131072 + i];
    fpool[i] = s;
  } else if (b < 768) {
    int i = (b - 512) * 256 + t;
    float s = 0.f;
#pragma unroll
    for (int z = 0; z < 16; ++z) s += ss_part[z * 65536 + i];
    float q = s * s;
#pragma unroll
    for (int o = 32; o; o >>= 1) q += __shfl_xor(q, o);
    if ((t & 63) == 0) sr[t >> 6] = q;
    __syncthreads();
    if (t == 0) atomicAdd(&scal[2], sr[0] + sr[1] + sr[2] + sr[3]);
  } else {
    int i = (b - 768) * 256 + t;
    float s = 0.f;
#pragma unroll
    for (int z = 0; z < 16; ++z) s += ap_part[z * 65536 + i];
    apool[i] = s;
    if (i % 257 == 0) atomicAdd(&scal[3], s);
  }
}

__launch_bounds__(64)
__global__ void finalize_k(const float* __restrict__ scal,
                           float* __restrict__ olink, float* __restrict__ oent) {
  if (threadIdx.x == 0) {
    float val = scal[0] - 2.f * scal[3] + scal[2];
    *olink = sqrtf(fmaxf(val, 0.f)) / ((float)Nn * (float)Nn);
    *oent  = scal[1] / (float)Nn;
  }
}

// ---------------- launch ----------------
extern "C" void kernel_launch(void* const* d_in, const int* in_sizes, int n_in,
                              void* d_out, int out_size, void* d_ws, size_t ws_size,
                              hipStream_t stream) {
  const float* F    = (const float*)d_in[0];
  const float* Adj  = (const float*)d_in[1];
  const float* W    = (const float*)d_in[2];
  const float* bias = (const float*)d_in[3];
  float* out = (float*)d_out;
  char* ws = (char*)d_ws;

  u16*  FbfPan  = (u16*)(ws + 0);           // 8 MB (dead after G1; overlaid by parts)
  u16*  parts   = (u16*)(ws + 0);           // 8 x 4 MB bf16 G2 partials (32 MB)
  u16*  spb     = (u16*)(ws + 33554432);    // 4 MB
  u16*  spTpan  = (u16*)(ws + 37748736);    // 4 MB
  u16*  Ppan    = (u16*)(ws + 41943040);    // 4 MB
  float* fp_part = (float*)(ws + 46137344); // 8 MB (16 x 131072 f32)
  float* ss_part = (float*)(ws + 54525952); // 4 MB (16 x 65536 f32)
  float* ap_part = (float*)(ws + 58720256); // 4 MB (16 x 65536 f32)
  float* cs     = (float*)(ws + 62914560);  // 1 KB
  float* scal   = (float*)(ws + 62915584);  // [0]=sumA2 [1]=ent [2]=frob [3]=trace

  float* fpool  = out;
  float* assign = out + 131072;
  float* apool  = out + 2228224;
  float* olink  = out + 2293760;
  float* oent   = out + 2293761;

  cvtF_panel<<<2049, 256, 0, stream>>>(F, FbfPan, cs, scal);

  // G1: logits = F @ W (W f32 converted on the fly) -> assign, softmax in place
  gemm2<false, false, 0, 2><<<dim3(4, 32, 1), 256, 0, stream>>>(
      FbfPan, 16, W, Kk, assign, Kk, Dd, 0, nullptr, 0);
  softmax_rows<<<2048, 256, 0, stream>>>(assign, bias);
  colsum_k<<<64, 256, 0, stream>>>(assign, cs);
  make_sp_all<<<256, 256, 0, stream>>>(assign, cs, spb, spTpan, &scal[1]);

  // G4: features_pooled partials = spT @ F (16 z-chunks, plain f32 stores)
  gemm2<false, false, 0, 2><<<dim3(8, 1, 16), 256, 0, stream>>>(
      spTpan, 256, F, Dd, fp_part, Dd, Nn / 16, 131072, nullptr, 1);
  // G5: spTsp partials = spT @ sp
  gemm2<true, false, 0, 2><<<dim3(4, 1, 16), 256, 0, stream>>>(
      spTpan, 256, spb, Kk, ss_part, Kk, Nn / 16, 65536, nullptr, 1);
  // G2: P = spT @ A: 8 bf16 partials + fused sum(A^2), XCD-chunked, 4 blk/CU
  gemm2<false, true, 1, 4><<<dim3(128, 1, 8), 256, 0, stream>>>(
      spTpan, 256, Adj, Nn, parts, Nn, Nn / 8, (size_t)Kk * Nn, &scal[0], 1);
  combine_P<<<1024, 256, 0, stream>>>(parts, Ppan);
  // G3: adjacency_pooled partials = P @ sp
  gemm2<true, false, 0, 2><<<dim3(4, 1, 16), 256, 0, stream>>>(
      Ppan, 256, spb, Kk, ap_part, Kk, Nn / 16, 65536, nullptr, 1);

  combine3<<<1024, 256, 0, stream>>>(fp_part, ss_part, ap_part, fpool, apool, scal);
  finalize_k<<<1, 64, 0, stream>>>(scal, olink, oent);
}

// Round 15
// 181.715 us; speedup vs baseline: 1.6355x; 1.1047x over previous
//
#include <hip/hip_runtime.h>

// DiffPooling on MI355X (gfx950).
// outputs f32 concat: features_pooled (256x512), assignments (8192x256),
// adjacency_pooled (256x256), link_loss, ent_loss.
// link_loss: ||A - sp sp^T||_F^2 = sum(A^2) - 2*tr(adj_pooled) + ||sp^T sp||_F^2
//
// MFMA A-operands in "panel" format (stride-32 u16 rows, gll-linear):
//   offset_u16(p, m, k) = (p*256 + m)*32 + (k%32),  p = global_k/32
// R15 = R14 (200.7 us) + widen skinny grids: G1 z=2 (summed in softmax),
// G4+G5 merged as gemm45 (384 blocks, one f32 path, inv_cs folded into
// combine3 -- R12-refchecked identity), G3 z=32 with B=assign. NO threadfence
// anywhere (R13/R14 A/B: all-thread __threadfence costs ~60 us).

typedef unsigned short u16;
typedef __bf16 bf16x8 __attribute__((ext_vector_type(8)));
typedef float f32x4 __attribute__((ext_vector_type(4)));
typedef float float8_t __attribute__((ext_vector_type(8)));
typedef unsigned short ushort8_t __attribute__((ext_vector_type(8)));

#define Nn 8192
#define Dd 512
#define Kk 256

__device__ __forceinline__ u16 f2bf(float f) {
  unsigned int u = __builtin_bit_cast(unsigned int, f);
  u += 0x7FFFu + ((u >> 16) & 1u);   // RNE
  return (u16)(u >> 16);
}
__device__ __forceinline__ float bf2f(u16 h) {
  return __builtin_bit_cast(float, (unsigned int)h << 16);
}
__device__ __forceinline__ void gll16(const void* g, void* l) {
  __builtin_amdgcn_global_load_lds(
      (const __attribute__((address_space(1))) unsigned int*)g,
      (__attribute__((address_space(3))) unsigned int*)l, 16, 0, 0);
}

// ---------------- panel-A bf16 MFMA GEMM, counted-vmcnt pipeline ----------------
// C(256 x 64 per block) = Apanel @ B(row-major f32, ldb; ->bf16 on the fly)
// 256 threads / 4 waves, wave tile 64x64, BK=32, double-buffered LDS, 40960 B.
// Per step t: gllA(other, t+1)[4] ; storeB(cur) [implicit wait drains B(t)+A(t)] ;
//             loadB(t+1)[8] ; s_waitcnt vmcnt(12) lgkmcnt(0) ; barrier ;
//             MFMA(cur) ; barrier.
// OUTKIND: 0 = f32 store via LDS at Cv + bz*zstride, 1 = bf16 z-partial (G2).
template <bool SUMSQ, int OUTKIND, int OCC>
__launch_bounds__(256, OCC)
__global__ void gemm2(const u16* __restrict__ Apan, int ppmb,
                      const float* __restrict__ Bv, int ldb,
                      void* __restrict__ Cv, int ldc,
                      int kchunk, size_t zstride,
                      float* __restrict__ sumsq, int swz) {
  __shared__ alignas(16) u16 SH[2 * 8192 + 2 * 2048];  // 40960 B exactly
  float* sred = (float*)&SH[20472];                    // last 16 B of SH

  int bx = blockIdx.x, bz = blockIdx.z;
  if (swz) {  // XCD-chunked bijective remap (total % 8 == 0)
    int gx = gridDim.x, tot = gx * gridDim.z;
    int f = bx + gx * bz;
    int l = (f & 7) * (tot >> 3) + (f >> 3);
    bx = l % gx; bz = l / gx;
  }
  const int tid = threadIdx.x, wv = tid >> 6, lane = tid & 63;
  const int l15 = lane & 15, g = lane >> 4;
  const int col0 = bx * 64;
  const int row0 = blockIdx.y * 256;
  const int kbeg = bz * kchunk;
  const int steps = kchunk >> 5;
  const u16* pbase = Apan + (size_t)(blockIdx.y * ppmb + (kbeg >> 5)) * 8192;

  float ss = 0.f;
  float8_t rb;

  auto loadB = [&](int t) {   // thread owns column (col0+lane), rows wv*8..+7
    const int kq = kbeg + t * 32 + wv * 8;
    const float* p = Bv + (size_t)kq * ldb + col0 + lane;
#pragma unroll
    for (int i = 0; i < 8; ++i) rb[i] = p[(size_t)i * ldb];
  };
  auto storeB = [&](int buf) {  // pack 8 k-elems of one col -> one b128
    ushort8_t h;
#pragma unroll
    for (int i = 0; i < 8; ++i) {
      h[i] = f2bf(rb[i]);
      if constexpr (SUMSQ) ss += rb[i] * rb[i];
    }
    *(uint4*)&SH[16384 + buf * 2048 + lane * 32 + wv * 8] = __builtin_bit_cast(uint4, h);
  };
  auto gllA = [&](int buf, int t) {      // 16 KB panel tile -> LDS, linear, coalesced
    const char* gp = (const char*)(pbase + (size_t)t * 8192) + wv * 4096 + lane * 16;
    char* lp = (char*)&SH[buf * 8192] + wv * 4096;
#pragma unroll
    for (int r = 0; r < 4; ++r) gll16(gp + r * 1024, lp + r * 1024);
  };

  f32x4 acc[4][4];
#pragma unroll
  for (int i = 0; i < 4; ++i)
#pragma unroll
    for (int j = 0; j < 4; ++j) acc[i][j] = (f32x4){0.f, 0.f, 0.f, 0.f};

  auto comp = [&](int buf) {
    const u16* as = &SH[buf * 8192];
    const u16* bs = &SH[16384 + buf * 2048];
    bf16x8 afr[4], bfr[4];
#pragma unroll
    for (int j = 0; j < 4; ++j)
      bfr[j] = *(const bf16x8*)(bs + (j * 16 + l15) * 32 + g * 8);
#pragma unroll
    for (int i = 0; i < 4; ++i)
      afr[i] = *(const bf16x8*)(as + (wv * 64 + i * 16 + l15) * 32 + g * 8);
#pragma unroll
    for (int i = 0; i < 4; ++i)
#pragma unroll
      for (int j = 0; j < 4; ++j)
        acc[i][j] = __builtin_amdgcn_mfma_f32_16x16x32_bf16(afr[i], bfr[j], acc[i][j], 0, 0, 0);
  };

  // prologue: A(0), B(0) in flight
  gllA(0, 0);
  loadB(0);
  const int last = steps - 1;

  for (int t = 0; t < steps; ++t) {
    const int cur = t & 1;
    gllA(1 - cur, (t + 1 < last) ? t + 1 : last);
    storeB(cur);                          // implicit wait: drains A(t)+B(t)
    loadB((t + 1 < last) ? t + 1 : last);
    asm volatile("s_waitcnt vmcnt(12) lgkmcnt(0)" ::: "memory");
    __builtin_amdgcn_s_barrier();
    __builtin_amdgcn_sched_barrier(0);
    comp(cur);
    __builtin_amdgcn_sched_barrier(0);
    __builtin_amdgcn_s_barrier();
  }
  // full drain before LDS reuse in epilogues
  asm volatile("s_waitcnt vmcnt(0) lgkmcnt(0)" ::: "memory");
  __builtin_amdgcn_s_barrier();

  // epilogues (C/D layout m89-verified: col = j*16+l15, row = wv*64+i*16+g*4+r)
  if constexpr (OUTKIND == 0) {          // f32 via LDS, two 128-row halves
    float* Cz = (float*)Cv + (size_t)bz * zstride;
    float* sf = (float*)SH;              // [128][68] f32 (34816 B)
#pragma unroll
    for (int h = 0; h < 2; ++h) {
      __syncthreads();
      if ((wv >> 1) == h) {
#pragma unroll
        for (int i = 0; i < 4; ++i)
#pragma unroll
          for (int j = 0; j < 4; ++j)
#pragma unroll
            for (int r = 0; r < 4; ++r)
              sf[((wv & 1) * 64 + i * 16 + g * 4 + r) * 68 + j * 16 + l15] = acc[i][j][r];
      }
      __syncthreads();
#pragma unroll
      for (int e = 0; e < 8; ++e) {     // 2048 float4s = full 128x64 tile
        int idx2 = tid + e * 256;
        int m = idx2 >> 4, c4 = (idx2 & 15) * 4;
        float4 v = *(const float4*)(sf + m * 68 + c4);
        *(float4*)(Cz + (size_t)(row0 + h * 128 + m) * ldc + col0 + c4) = v;
      }
    }
  } else {                               // bf16 linear z-partial via LDS (G2)
    u16* C = (u16*)Cv + (size_t)bz * zstride;
    u16* sb = SH;                        // [256][72] u16 (36864 B)
#pragma unroll
    for (int i = 0; i < 4; ++i)
#pragma unroll
      for (int j = 0; j < 4; ++j)
#pragma unroll
        for (int r = 0; r < 4; ++r)
          sb[(wv * 64 + i * 16 + g * 4 + r) * 72 + j * 16 + l15] = f2bf(acc[i][j][r]);
    __syncthreads();
#pragma unroll
    for (int e = 0; e < 8; ++e) {
      int m = (tid >> 3) + e * 32;
      uint4 v = *(const uint4*)(sb + m * 72 + (tid & 7) * 8);
      *(uint4*)(C + (size_t)m * ldc + col0 + (tid & 7) * 8) = v;
    }
  }

  if constexpr (SUMSQ) {
#pragma unroll
    for (int o = 32; o; o >>= 1) ss += __shfl_xor(ss, o);
    __syncthreads();
    if (lane == 0) sred[wv] = ss;
    __syncthreads();
    if (tid == 0) atomicAdd(sumsq, sred[0] + sred[1] + sred[2] + sred[3]);
  }
}

// ---------------- merged G4+G5 (384 blocks, one f32 hot path) ----------------
// b<256: G4 fp_part(bz) = spT @ F cols [64bx,64bx+64), z=32 (kchunk 256)
// b>=256: G5 ss_part(bz) = spT @ assign (inv_cs folded later), z=32
__launch_bounds__(256, 2)
__global__ void gemm45(const u16* __restrict__ spTpan,
                       const float* __restrict__ F, float* __restrict__ fp_part,
                       const float* __restrict__ assign, float* __restrict__ ss_part) {
  __shared__ alignas(16) u16 SH[2 * 8192 + 2 * 2048];

  const int b = blockIdx.x;
  int bx, bz, ldb, ldc;
  const float* Bf;
  float* Cz;
  if (b < 256) {
    bx = b & 7; bz = b >> 3;
    Bf = F; ldb = Dd; ldc = Dd;
    Cz = fp_part + (size_t)bz * 131072;
  } else {
    int lb = b - 256;
    bx = lb & 3; bz = lb >> 2;
    Bf = assign; ldb = Kk; ldc = Kk;
    Cz = ss_part + (size_t)bz * 65536;
  }
  const int tid = threadIdx.x, wv = tid >> 6, lane = tid & 63;
  const int l15 = lane & 15, g = lane >> 4;
  const int col0 = bx * 64;
  const int kbeg = bz * 256;
  const u16* pbase = spTpan + (size_t)(kbeg >> 5) * 8192;

  float8_t rb;
  auto loadB = [&](int t) {
    const int kq = kbeg + t * 32 + wv * 8;
    const float* p = Bf + (size_t)kq * ldb + col0 + lane;
#pragma unroll
    for (int i = 0; i < 8; ++i) rb[i] = p[(size_t)i * ldb];
  };
  auto storeB = [&](int buf) {
    ushort8_t h;
#pragma unroll
    for (int i = 0; i < 8; ++i) h[i] = f2bf(rb[i]);
    *(uint4*)&SH[16384 + buf * 2048 + lane * 32 + wv * 8] = __builtin_bit_cast(uint4, h);
  };
  auto gllA = [&](int buf, int t) {
    const char* gp = (const char*)(pbase + (size_t)t * 8192) + wv * 4096 + lane * 16;
    char* lp = (char*)&SH[buf * 8192] + wv * 4096;
#pragma unroll
    for (int r = 0; r < 4; ++r) gll16(gp + r * 1024, lp + r * 1024);
  };

  f32x4 acc[4][4];
#pragma unroll
  for (int i = 0; i < 4; ++i)
#pragma unroll
    for (int j = 0; j < 4; ++j) acc[i][j] = (f32x4){0.f, 0.f, 0.f, 0.f};

  auto comp = [&](int buf) {
    const u16* as = &SH[buf * 8192];
    const u16* bs = &SH[16384 + buf * 2048];
    bf16x8 afr[4], bfr[4];
#pragma unroll
    for (int j = 0; j < 4; ++j)
      bfr[j] = *(const bf16x8*)(bs + (j * 16 + l15) * 32 + g * 8);
#pragma unroll
    for (int i = 0; i < 4; ++i)
      afr[i] = *(const bf16x8*)(as + (wv * 64 + i * 16 + l15) * 32 + g * 8);
#pragma unroll
    for (int i = 0; i < 4; ++i)
#pragma unroll
      for (int j = 0; j < 4; ++j)
        acc[i][j] = __builtin_amdgcn_mfma_f32_16x16x32_bf16(afr[i], bfr[j], acc[i][j], 0, 0, 0);
  };

  gllA(0, 0);
  loadB(0);
  const int last = 7;                    // steps = 8
  for (int t = 0; t < 8; ++t) {
    const int cur = t & 1;
    gllA(1 - cur, (t + 1 < last) ? t + 1 : last);
    storeB(cur);
    loadB((t + 1 < last) ? t + 1 : last);
    asm volatile("s_waitcnt vmcnt(12) lgkmcnt(0)" ::: "memory");
    __builtin_amdgcn_s_barrier();
    __builtin_amdgcn_sched_barrier(0);
    comp(cur);
    __builtin_amdgcn_sched_barrier(0);
    __builtin_amdgcn_s_barrier();
  }
  asm volatile("s_waitcnt vmcnt(0) lgkmcnt(0)" ::: "memory");
  __builtin_amdgcn_s_barrier();

  float* sf = (float*)SH;                // [128][68]
#pragma unroll
  for (int h = 0; h < 2; ++h) {
    __syncthreads();
    if ((wv >> 1) == h) {
#pragma unroll
      for (int i = 0; i < 4; ++i)
#pragma unroll
        for (int j = 0; j < 4; ++j)
#pragma unroll
          for (int r = 0; r < 4; ++r)
            sf[((wv & 1) * 64 + i * 16 + g * 4 + r) * 68 + j * 16 + l15] = acc[i][j][r];
    }
    __syncthreads();
#pragma unroll
    for (int e = 0; e < 8; ++e) {
      int idx2 = tid + e * 256;
      int m = idx2 >> 4, c4 = (idx2 & 15) * 4;
      float4 v = *(const float4*)(sf + m * 68 + c4);
      *(float4*)(Cz + (size_t)(h * 128 + m) * ldc + col0 + c4) = v;
    }
  }
}

// ---------------- producers / small kernels ----------------
// F f32 -> panel bf16; extra last block zeroes cs + scal
__launch_bounds__(256)
__global__ void cvtF_panel(const float* __restrict__ F, u16* __restrict__ pan,
                           float* __restrict__ cs, float* __restrict__ scal) {
  if (blockIdx.x == 2048) {
    int t = threadIdx.x;
    float4 z = {0.f, 0.f, 0.f, 0.f};
    if (t < 64) ((float4*)cs)[t] = z;
    else if (t == 64) ((float4*)scal)[0] = z;   // scal[0..3]
    return;
  }
  int idx = blockIdx.x * 256 + threadIdx.x;      // 524288 groups of 8
  int m = idx >> 6, k0 = (idx & 63) * 8;
  float4 a = *(const float4*)(F + (size_t)m * Dd + k0);
  float4 b = *(const float4*)(F + (size_t)m * Dd + k0 + 4);
  ushort8_t h;
  h[0] = f2bf(a.x); h[1] = f2bf(a.y); h[2] = f2bf(a.z); h[3] = f2bf(a.w);
  h[4] = f2bf(b.x); h[5] = f2bf(b.y); h[6] = f2bf(b.z); h[7] = f2bf(b.w);
  int mb = m >> 8, mr = m & 255, p = k0 >> 5, c = k0 & 31;
  *(uint4*)(pan + ((size_t)(mb * 16 + p) * 256 + mr) * 32 + c) = __builtin_bit_cast(uint4, h);
}

// wave-per-row softmax over SUM of two G1 z-partials + bias.
__launch_bounds__(256)
__global__ void softmax_rows(const float* __restrict__ lg, float* __restrict__ io,
                             const float* __restrict__ bias) {
  int wv = threadIdx.x >> 6, lane = threadIdx.x & 63;
  int n = blockIdx.x * 4 + wv;
  float4 b4 = ((const float4*)bias)[lane];
  float4 p0 = ((const float4*)(lg + (size_t)n * Kk))[lane];
  float4 p1 = ((const float4*)(lg + 2097152 + (size_t)n * Kk))[lane];
  float4 x = {p0.x + p1.x + b4.x, p0.y + p1.y + b4.y,
              p0.z + p1.z + b4.z, p0.w + p1.w + b4.w};
  float m = fmaxf(fmaxf(x.x, x.y), fmaxf(x.z, x.w));
#pragma unroll
  for (int o = 32; o; o >>= 1) m = fmaxf(m, __shfl_xor(m, o));
  float4 e = {__expf(x.x - m), __expf(x.y - m), __expf(x.z - m), __expf(x.w - m)};
  float s = e.x + e.y + e.z + e.w;
#pragma unroll
  for (int o = 32; o; o >>= 1) s += __shfl_xor(s, o);
  float inv = 1.f / s;
  e.x *= inv; e.y *= inv; e.z *= inv; e.w *= inv;
  ((float4*)(io + (size_t)n * Kk))[lane] = e;
}

// colsum: 64 blocks x 128 rows; float4.
__launch_bounds__(256)
__global__ void colsum_k(const float* __restrict__ a, float* __restrict__ cs) {
  __shared__ float4 red[4][64];
  int t = threadIdx.x, rg = t >> 6, c = t & 63;
  size_t n0 = (size_t)blockIdx.x * 128 + rg * 32;
  float4 s = {0.f, 0.f, 0.f, 0.f};
  for (int i = 0; i < 32; ++i) {
    float4 v = ((const float4*)(a + (n0 + i) * Kk))[c];
    s.x += v.x; s.y += v.y; s.z += v.z; s.w += v.w;
  }
  red[rg][c] = s;
  __syncthreads();
  if (rg == 0) {
    float4 a1 = red[1][c], a2 = red[2][c], a3 = red[3][c];
    s.x += a1.x + a2.x + a3.x; s.y += a1.y + a2.y + a3.y;
    s.z += a1.z + a2.z + a3.z; s.w += a1.w + a2.w + a3.w;
    atomicAdd(&cs[c * 4 + 0], s.x); atomicAdd(&cs[c * 4 + 1], s.y);
    atomicAdd(&cs[c * 4 + 2], s.z); atomicAdd(&cs[c * 4 + 3], s.w);
  }
}

// spT panel (inv folded) + entropy. block p: rows [32p,32p+32), thread = k.
__launch_bounds__(256)
__global__ void make_sp_pan(const float* __restrict__ a, const float* __restrict__ cs,
                            u16* __restrict__ pan, float* __restrict__ ent_sum) {
  __shared__ float sr[4];
  int p = blockIdx.x, k = threadIdx.x;
  float inv = 1.f / (cs[k] + 1e-8f);
  int n0 = p * 32;
  float ent = 0.f;
  ushort8_t h[4];
#pragma unroll
  for (int q = 0; q < 4; ++q) {
#pragma unroll
    for (int j = 0; j < 8; ++j) {
      float v = a[(size_t)(n0 + q * 8 + j) * Kk + k] * inv;
      h[q][j] = f2bf(v);
      ent -= v * __logf(v + 1e-15f);
    }
  }
  u16* dst = pan + ((size_t)p * 256 + k) * 32;
  *(uint4*)(dst + 0)  = __builtin_bit_cast(uint4, h[0]);
  *(uint4*)(dst + 8)  = __builtin_bit_cast(uint4, h[1]);
  *(uint4*)(dst + 16) = __builtin_bit_cast(uint4, h[2]);
  *(uint4*)(dst + 24) = __builtin_bit_cast(uint4, h[3]);
#pragma unroll
  for (int o = 32; o; o >>= 1) ent += __shfl_xor(ent, o);
  if ((k & 63) == 0) sr[k >> 6] = ent;
  __syncthreads();
  if (k == 0) atomicAdd(ent_sum, sr[0] + sr[1] + sr[2] + sr[3]);
}

// sum 8 bf16 partials -> P panel (stride-32)
__launch_bounds__(256)
__global__ void combine_P(const u16* __restrict__ part, u16* __restrict__ pan) {
  int idx = blockIdx.x * 256 + threadIdx.x;      // 262144
  int m = idx >> 10, kk8 = idx & 1023;
  size_t off = (size_t)m * Nn + kk8 * 8;
  float8_t s = {0.f, 0.f, 0.f, 0.f, 0.f, 0.f, 0.f, 0.f};
#pragma unroll
  for (int z = 0; z < 8; ++z) {
    ushort8_t v = __builtin_bit_cast(ushort8_t,
        *(const uint4*)(part + (size_t)z * Kk * Nn + off));
#pragma unroll
    for (int j = 0; j < 8; ++j) s[j] += bf2f(v[j]);
  }
  ushort8_t h;
#pragma unroll
  for (int j = 0; j < 8; ++j) h[j] = f2bf(s[j]);
  int p = kk8 >> 2, c = (kk8 & 3) * 8;
  *(uint4*)(pan + ((size_t)p * 256 + m) * 32 + c) = __builtin_bit_cast(uint4, h);
}

// combine z-partials; inv_cs column scaling for ss/ap (R12-refchecked).
// blocks 0-511: fpool (32 slices); 512-767: frob(spTsp) (32, x inv);
// 768-1023: apool (32, x inv) + trace.
__launch_bounds__(256)
__global__ void combine3(const float* __restrict__ fp_part, const float* __restrict__ ss_part,
                         const float* __restrict__ ap_part, const float* __restrict__ cs,
                         float* __restrict__ fpool, float* __restrict__ apool,
                         float* __restrict__ scal) {
  __shared__ float sr[4];
  int b = blockIdx.x, t = threadIdx.x;
  if (b < 512) {
    int i = b * 256 + t;
    float s = 0.f;
#pragma unroll
    for (int z = 0; z < 32; ++z) s += fp_part[z * 131072 + i];
    fpool[i] = s;
  } else if (b < 768) {
    int i = (b - 512) * 256 + t;
    float s = 0.f;
#pragma unroll
    for (int z = 0; z < 32; ++z) s += ss_part[z * 65536 + i];
    s *= 1.f / (cs[i & 255] + 1e-8f);
    float q = s * s;
#pragma unroll
    for (int o = 32; o; o >>= 1) q += __shfl_xor(q, o);
    if ((t & 63) == 0) sr[t >> 6] = q;
    __syncthreads();
    if (t == 0) atomicAdd(&scal[2], sr[0] + sr[1] + sr[2] + sr[3]);
  } else {
    int i = (b - 768) * 256 + t;
    float s = 0.f;
#pragma unroll
    for (int z = 0; z < 32; ++z) s += ap_part[z * 65536 + i];
    s *= 1.f / (cs[i & 255] + 1e-8f);
    apool[i] = s;
    if (i % 257 == 0) atomicAdd(&scal[3], s);
  }
}

__launch_bounds__(64)
__global__ void finalize_k(const float* __restrict__ scal,
                           float* __restrict__ olink, float* __restrict__ oent) {
  if (threadIdx.x == 0) {
    float val = scal[0] - 2.f * scal[3] + scal[2];
    *olink = sqrtf(fmaxf(val, 0.f)) / ((float)Nn * (float)Nn);
    *oent  = scal[1] / (float)Nn;
  }
}

// ---------------- launch ----------------
extern "C" void kernel_launch(void* const* d_in, const int* in_sizes, int n_in,
                              void* d_out, int out_size, void* d_ws, size_t ws_size,
                              hipStream_t stream) {
  const float* F    = (const float*)d_in[0];
  const float* Adj  = (const float*)d_in[1];
  const float* W    = (const float*)d_in[2];
  const float* bias = (const float*)d_in[3];
  float* out = (float*)d_out;
  char* ws = (char*)d_ws;

  u16*  FbfPan  = (u16*)(ws + 0);           // 8 MB (dead after G1; overlaid by parts)
  u16*  parts   = (u16*)(ws + 0);           // 8 x 4 MB bf16 G2 linear partials
  u16*  spTpan  = (u16*)(ws + 33554432);    // 4 MB
  u16*  Ppan    = (u16*)(ws + 37748736);    // 4 MB
  float* lg_part = (float*)(ws + 41943040); // 16 MB (2 x 2097152 f32)
  float* fp_part = (float*)(ws + 58720256); // 16 MB (32 x 131072 f32)
  float* ss_part = (float*)(ws + 75497472); // 8 MB (32 x 65536 f32)
  float* ap_part = (float*)(ws + 83886080); // 8 MB (32 x 65536 f32)
  float* cs     = (float*)(ws + 92274688);  // 1 KB
  float* scal   = (float*)(ws + 92275712);  // [0]=sumA2 [1]=ent [2]=frob [3]=trace

  float* fpool  = out;
  float* assign = out + 131072;
  float* apool  = out + 2228224;
  float* olink  = out + 2293760;
  float* oent   = out + 2293761;

  cvtF_panel<<<2049, 256, 0, stream>>>(F, FbfPan, cs, scal);

  // G1: logit partials = F @ W (z=2, 256 blocks); summed inside softmax
  gemm2<false, 0, 2><<<dim3(4, 32, 2), 256, 0, stream>>>(
      FbfPan, 16, W, Kk, lg_part, Kk, 256, 2097152, nullptr, 0);
  softmax_rows<<<2048, 256, 0, stream>>>(lg_part, assign, bias);
  colsum_k<<<64, 256, 0, stream>>>(assign, cs);
  make_sp_pan<<<256, 256, 0, stream>>>(assign, cs, spTpan, &scal[1]);

  // G4+G5 merged: 384 blocks, z=32 each, one f32 hot path
  gemm45<<<384, 256, 0, stream>>>(spTpan, F, fp_part, assign, ss_part);

  // G2: P = spT @ A: 8 bf16 partials + fused sum(A^2), XCD-chunked, 4 blk/CU
  gemm2<true, 1, 4><<<dim3(128, 1, 8), 256, 0, stream>>>(
      spTpan, 256, Adj, Nn, parts, Nn, Nn / 8, (size_t)Kk * Nn, &scal[0], 1);
  combine_P<<<1024, 256, 0, stream>>>(parts, Ppan);

  // G3: apool raw partials = P @ assign (z=32, 128 blocks; inv folded later)
  gemm2<false, 0, 2><<<dim3(4, 1, 32), 256, 0, stream>>>(
      Ppan, 256, assign, Kk, ap_part, Kk, 256, 65536, nullptr, 1);

  combine3<<<1024, 256, 0, stream>>>(fp_part, ss_part, ap_part, cs, fpool, apool, scal);
  finalize_k<<<1, 64, 0, stream>>>(scal, olink, oent);
}

// Round 16
// 175.296 us; speedup vs baseline: 1.6954x; 1.0366x over previous
//
#include <hip/hip_runtime.h>

// DiffPooling on MI355X (gfx950).
// outputs f32 concat: features_pooled (256x512), assignments (8192x256),
// adjacency_pooled (256x256), link_loss, ent_loss.
// link_loss: ||A - sp sp^T||_F^2 = sum(A^2) - 2*tr(adj_pooled) + ||sp^T sp||_F^2
//
// MFMA A-operands in "panel" format (stride-32 u16 rows, gll-linear):
//   offset_u16(p, m, k) = (p*256 + m)*32 + (k%32),  p = global_k/32
// R16 = R15 (181.7 us) + cvtF fused into G1 (gemm1 reg-stages A directly from
// F f32; panel conversion inline) + cs/scal zeroing moved to softmax block 2048.
// NO threadfence anywhere (R13/R14 A/B: all-thread fence costs ~60 us).

typedef unsigned short u16;
typedef __bf16 bf16x8 __attribute__((ext_vector_type(8)));
typedef float f32x4 __attribute__((ext_vector_type(4)));
typedef float float8_t __attribute__((ext_vector_type(8)));
typedef unsigned short ushort8_t __attribute__((ext_vector_type(8)));

#define Nn 8192
#define Dd 512
#define Kk 256

__device__ __forceinline__ u16 f2bf(float f) {
  unsigned int u = __builtin_bit_cast(unsigned int, f);
  u += 0x7FFFu + ((u >> 16) & 1u);   // RNE
  return (u16)(u >> 16);
}
__device__ __forceinline__ float bf2f(u16 h) {
  return __builtin_bit_cast(float, (unsigned int)h << 16);
}
__device__ __forceinline__ void gll16(const void* g, void* l) {
  __builtin_amdgcn_global_load_lds(
      (const __attribute__((address_space(1))) unsigned int*)g,
      (__attribute__((address_space(3))) unsigned int*)l, 16, 0, 0);
}

// ---------------- panel-A bf16 MFMA GEMM, counted-vmcnt pipeline ----------------
// C(256 x 64 per block) = Apanel @ B(row-major f32, ldb; ->bf16 on the fly)
// Per step t: gllA(other, t+1)[4] ; storeB(cur) [implicit wait] ; loadB(t+1)[8] ;
//             vmcnt(12) lgkmcnt(0) ; barrier ; MFMA(cur) ; barrier.
// OUTKIND: 0 = f32 store via LDS at Cv + bz*zstride, 1 = bf16 z-partial (G2).
template <bool SUMSQ, int OUTKIND, int OCC>
__launch_bounds__(256, OCC)
__global__ void gemm2(const u16* __restrict__ Apan, int ppmb,
                      const float* __restrict__ Bv, int ldb,
                      void* __restrict__ Cv, int ldc,
                      int kchunk, size_t zstride,
                      float* __restrict__ sumsq, int swz) {
  __shared__ alignas(16) u16 SH[2 * 8192 + 2 * 2048];  // 40960 B exactly
  float* sred = (float*)&SH[20472];                    // last 16 B of SH

  int bx = blockIdx.x, bz = blockIdx.z;
  if (swz) {  // XCD-chunked bijective remap (total % 8 == 0)
    int gx = gridDim.x, tot = gx * gridDim.z;
    int f = bx + gx * bz;
    int l = (f & 7) * (tot >> 3) + (f >> 3);
    bx = l % gx; bz = l / gx;
  }
  const int tid = threadIdx.x, wv = tid >> 6, lane = tid & 63;
  const int l15 = lane & 15, g = lane >> 4;
  const int col0 = bx * 64;
  const int row0 = blockIdx.y * 256;
  const int kbeg = bz * kchunk;
  const int steps = kchunk >> 5;
  const u16* pbase = Apan + (size_t)(blockIdx.y * ppmb + (kbeg >> 5)) * 8192;

  float ss = 0.f;
  float8_t rb;

  auto loadB = [&](int t) {   // thread owns column (col0+lane), rows wv*8..+7
    const int kq = kbeg + t * 32 + wv * 8;
    const float* p = Bv + (size_t)kq * ldb + col0 + lane;
#pragma unroll
    for (int i = 0; i < 8; ++i) rb[i] = p[(size_t)i * ldb];
  };
  auto storeB = [&](int buf) {  // pack 8 k-elems of one col -> one b128
    ushort8_t h;
#pragma unroll
    for (int i = 0; i < 8; ++i) {
      h[i] = f2bf(rb[i]);
      if constexpr (SUMSQ) ss += rb[i] * rb[i];
    }
    *(uint4*)&SH[16384 + buf * 2048 + lane * 32 + wv * 8] = __builtin_bit_cast(uint4, h);
  };
  auto gllA = [&](int buf, int t) {      // 16 KB panel tile -> LDS, linear, coalesced
    const char* gp = (const char*)(pbase + (size_t)t * 8192) + wv * 4096 + lane * 16;
    char* lp = (char*)&SH[buf * 8192] + wv * 4096;
#pragma unroll
    for (int r = 0; r < 4; ++r) gll16(gp + r * 1024, lp + r * 1024);
  };

  f32x4 acc[4][4];
#pragma unroll
  for (int i = 0; i < 4; ++i)
#pragma unroll
    for (int j = 0; j < 4; ++j) acc[i][j] = (f32x4){0.f, 0.f, 0.f, 0.f};

  auto comp = [&](int buf) {
    const u16* as = &SH[buf * 8192];
    const u16* bs = &SH[16384 + buf * 2048];
    bf16x8 afr[4], bfr[4];
#pragma unroll
    for (int j = 0; j < 4; ++j)
      bfr[j] = *(const bf16x8*)(bs + (j * 16 + l15) * 32 + g * 8);
#pragma unroll
    for (int i = 0; i < 4; ++i)
      afr[i] = *(const bf16x8*)(as + (wv * 64 + i * 16 + l15) * 32 + g * 8);
#pragma unroll
    for (int i = 0; i < 4; ++i)
#pragma unroll
      for (int j = 0; j < 4; ++j)
        acc[i][j] = __builtin_amdgcn_mfma_f32_16x16x32_bf16(afr[i], bfr[j], acc[i][j], 0, 0, 0);
  };

  // prologue: A(0), B(0) in flight
  gllA(0, 0);
  loadB(0);
  const int last = steps - 1;

  for (int t = 0; t < steps; ++t) {
    const int cur = t & 1;
    gllA(1 - cur, (t + 1 < last) ? t + 1 : last);
    storeB(cur);                          // implicit wait: drains A(t)+B(t)
    loadB((t + 1 < last) ? t + 1 : last);
    asm volatile("s_waitcnt vmcnt(12) lgkmcnt(0)" ::: "memory");
    __builtin_amdgcn_s_barrier();
    __builtin_amdgcn_sched_barrier(0);
    comp(cur);
    __builtin_amdgcn_sched_barrier(0);
    __builtin_amdgcn_s_barrier();
  }
  // full drain before LDS reuse in epilogues
  asm volatile("s_waitcnt vmcnt(0) lgkmcnt(0)" ::: "memory");
  __builtin_amdgcn_s_barrier();

  // epilogues (C/D layout m89-verified: col = j*16+l15, row = wv*64+i*16+g*4+r)
  if constexpr (OUTKIND == 0) {          // f32 via LDS, two 128-row halves
    float* Cz = (float*)Cv + (size_t)bz * zstride;
    float* sf = (float*)SH;              // [128][68] f32 (34816 B)
#pragma unroll
    for (int h = 0; h < 2; ++h) {
      __syncthreads();
      if ((wv >> 1) == h) {
#pragma unroll
        for (int i = 0; i < 4; ++i)
#pragma unroll
          for (int j = 0; j < 4; ++j)
#pragma unroll
            for (int r = 0; r < 4; ++r)
              sf[((wv & 1) * 64 + i * 16 + g * 4 + r) * 68 + j * 16 + l15] = acc[i][j][r];
      }
      __syncthreads();
#pragma unroll
      for (int e = 0; e < 8; ++e) {     // 2048 float4s = full 128x64 tile
        int idx2 = tid + e * 256;
        int m = idx2 >> 4, c4 = (idx2 & 15) * 4;
        float4 v = *(const float4*)(sf + m * 68 + c4);
        *(float4*)(Cz + (size_t)(row0 + h * 128 + m) * ldc + col0 + c4) = v;
      }
    }
  } else {                               // bf16 linear z-partial via LDS (G2)
    u16* C = (u16*)Cv + (size_t)bz * zstride;
    u16* sb = SH;                        // [256][72] u16 (36864 B)
#pragma unroll
    for (int i = 0; i < 4; ++i)
#pragma unroll
      for (int j = 0; j < 4; ++j)
#pragma unroll
        for (int r = 0; r < 4; ++r)
          sb[(wv * 64 + i * 16 + g * 4 + r) * 72 + j * 16 + l15] = f2bf(acc[i][j][r]);
    __syncthreads();
#pragma unroll
    for (int e = 0; e < 8; ++e) {
      int m = (tid >> 3) + e * 32;
      uint4 v = *(const uint4*)(sb + m * 72 + (tid & 7) * 8);
      *(uint4*)(C + (size_t)m * ldc + col0 + (tid & 7) * 8) = v;
    }
  }

  if constexpr (SUMSQ) {
#pragma unroll
    for (int o = 32; o; o >>= 1) ss += __shfl_xor(ss, o);
    __syncthreads();
    if (lane == 0) sred[wv] = ss;
    __syncthreads();
    if (tid == 0) atomicAdd(sumsq, sred[0] + sred[1] + sred[2] + sred[3]);
  }
}

// ---------------- G1 fused: logits = F @ W, A reg-staged directly from F ----------
// grid (4, 32, 2). Per step: storeA(cur) [8x cvt+b64]; storeB(cur); loadA(t+1)
// [8 dwordx4, 8 rows x 128B runs]; loadB(t+1)[8]; vmcnt(16); barrier; MFMA; barrier.
__launch_bounds__(256, 2)
__global__ void gemm1(const float* __restrict__ F, const float* __restrict__ W,
                      float* __restrict__ Cv, size_t zstride) {
  __shared__ alignas(16) u16 SH[2 * 8192 + 2 * 2048];

  const int tid = threadIdx.x, wv = tid >> 6, lane = tid & 63;
  const int l15 = lane & 15, g = lane >> 4;
  const int col0 = blockIdx.x * 64;
  const int row0 = blockIdx.y * 256;
  const int kbeg = blockIdx.z * 256;
  const int mrow = tid >> 3, kq4 = (tid & 7) * 4;   // A staging map

  float4 rA[8];
  float8_t rb;

  auto loadA = [&](int t) {
    const float* p = F + (size_t)(row0 + mrow) * Dd + kbeg + t * 32 + kq4;
#pragma unroll
    for (int i = 0; i < 8; ++i) rA[i] = *(const float4*)(p + (size_t)i * 32 * Dd);
  };
  auto storeA = [&](int buf) {
    u16* as = &SH[buf * 8192];
#pragma unroll
    for (int i = 0; i < 8; ++i) {
      ushort4 h = {f2bf(rA[i].x), f2bf(rA[i].y), f2bf(rA[i].z), f2bf(rA[i].w)};
      *(uint2*)(as + (mrow + i * 32) * 32 + kq4) = __builtin_bit_cast(uint2, h);
    }
  };
  auto loadB = [&](int t) {
    const int kq = kbeg + t * 32 + wv * 8;
    const float* p = W + (size_t)kq * Kk + col0 + lane;
#pragma unroll
    for (int i = 0; i < 8; ++i) rb[i] = p[(size_t)i * Kk];
  };
  auto storeB = [&](int buf) {
    ushort8_t h;
#pragma unroll
    for (int i = 0; i < 8; ++i) h[i] = f2bf(rb[i]);
    *(uint4*)&SH[16384 + buf * 2048 + lane * 32 + wv * 8] = __builtin_bit_cast(uint4, h);
  };

  f32x4 acc[4][4];
#pragma unroll
  for (int i = 0; i < 4; ++i)
#pragma unroll
    for (int j = 0; j < 4; ++j) acc[i][j] = (f32x4){0.f, 0.f, 0.f, 0.f};

  auto comp = [&](int buf) {
    const u16* as = &SH[buf * 8192];
    const u16* bs = &SH[16384 + buf * 2048];
    bf16x8 afr[4], bfr[4];
#pragma unroll
    for (int j = 0; j < 4; ++j)
      bfr[j] = *(const bf16x8*)(bs + (j * 16 + l15) * 32 + g * 8);
#pragma unroll
    for (int i = 0; i < 4; ++i)
      afr[i] = *(const bf16x8*)(as + (wv * 64 + i * 16 + l15) * 32 + g * 8);
#pragma unroll
    for (int i = 0; i < 4; ++i)
#pragma unroll
      for (int j = 0; j < 4; ++j)
        acc[i][j] = __builtin_amdgcn_mfma_f32_16x16x32_bf16(afr[i], bfr[j], acc[i][j], 0, 0, 0);
  };

  loadA(0);
  loadB(0);
  for (int t = 0; t < 8; ++t) {
    const int cur = t & 1;
    storeA(cur);                          // implicit wait drains A(t)
    storeB(cur);                          // implicit wait drains B(t)
    loadA((t + 1 < 8) ? t + 1 : 7);
    loadB((t + 1 < 8) ? t + 1 : 7);
    asm volatile("s_waitcnt vmcnt(16) lgkmcnt(0)" ::: "memory");
    __builtin_amdgcn_s_barrier();
    __builtin_amdgcn_sched_barrier(0);
    comp(cur);
    __builtin_amdgcn_sched_barrier(0);
    __builtin_amdgcn_s_barrier();
  }
  asm volatile("s_waitcnt vmcnt(0) lgkmcnt(0)" ::: "memory");
  __builtin_amdgcn_s_barrier();

  float* Cz = Cv + (size_t)blockIdx.z * zstride;
  float* sf = (float*)SH;                // [128][68] f32
#pragma unroll
  for (int h = 0; h < 2; ++h) {
    __syncthreads();
    if ((wv >> 1) == h) {
#pragma unroll
      for (int i = 0; i < 4; ++i)
#pragma unroll
        for (int j = 0; j < 4; ++j)
#pragma unroll
          for (int r = 0; r < 4; ++r)
            sf[((wv & 1) * 64 + i * 16 + g * 4 + r) * 68 + j * 16 + l15] = acc[i][j][r];
    }
    __syncthreads();
#pragma unroll
    for (int e = 0; e < 8; ++e) {
      int idx2 = tid + e * 256;
      int m = idx2 >> 4, c4 = (idx2 & 15) * 4;
      float4 v = *(const float4*)(sf + m * 68 + c4);
      *(float4*)(Cz + (size_t)(row0 + h * 128 + m) * Kk + col0 + c4) = v;
    }
  }
}

// ---------------- merged G4+G5 (384 blocks, one f32 hot path) ----------------
__launch_bounds__(256, 2)
__global__ void gemm45(const u16* __restrict__ spTpan,
                       const float* __restrict__ F, float* __restrict__ fp_part,
                       const float* __restrict__ assign, float* __restrict__ ss_part) {
  __shared__ alignas(16) u16 SH[2 * 8192 + 2 * 2048];

  const int b = blockIdx.x;
  int bx, bz, ldb, ldc;
  const float* Bf;
  float* Cz;
  if (b < 256) {
    bx = b & 7; bz = b >> 3;
    Bf = F; ldb = Dd; ldc = Dd;
    Cz = fp_part + (size_t)bz * 131072;
  } else {
    int lb = b - 256;
    bx = lb & 3; bz = lb >> 2;
    Bf = assign; ldb = Kk; ldc = Kk;
    Cz = ss_part + (size_t)bz * 65536;
  }
  const int tid = threadIdx.x, wv = tid >> 6, lane = tid & 63;
  const int l15 = lane & 15, g = lane >> 4;
  const int col0 = bx * 64;
  const int kbeg = bz * 256;
  const u16* pbase = spTpan + (size_t)(kbeg >> 5) * 8192;

  float8_t rb;
  auto loadB = [&](int t) {
    const int kq = kbeg + t * 32 + wv * 8;
    const float* p = Bf + (size_t)kq * ldb + col0 + lane;
#pragma unroll
    for (int i = 0; i < 8; ++i) rb[i] = p[(size_t)i * ldb];
  };
  auto storeB = [&](int buf) {
    ushort8_t h;
#pragma unroll
    for (int i = 0; i < 8; ++i) h[i] = f2bf(rb[i]);
    *(uint4*)&SH[16384 + buf * 2048 + lane * 32 + wv * 8] = __builtin_bit_cast(uint4, h);
  };
  auto gllA = [&](int buf, int t) {
    const char* gp = (const char*)(pbase + (size_t)t * 8192) + wv * 4096 + lane * 16;
    char* lp = (char*)&SH[buf * 8192] + wv * 4096;
#pragma unroll
    for (int r = 0; r < 4; ++r) gll16(gp + r * 1024, lp + r * 1024);
  };

  f32x4 acc[4][4];
#pragma unroll
  for (int i = 0; i < 4; ++i)
#pragma unroll
    for (int j = 0; j < 4; ++j) acc[i][j] = (f32x4){0.f, 0.f, 0.f, 0.f};

  auto comp = [&](int buf) {
    const u16* as = &SH[buf * 8192];
    const u16* bs = &SH[16384 + buf * 2048];
    bf16x8 afr[4], bfr[4];
#pragma unroll
    for (int j = 0; j < 4; ++j)
      bfr[j] = *(const bf16x8*)(bs + (j * 16 + l15) * 32 + g * 8);
#pragma unroll
    for (int i = 0; i < 4; ++i)
      afr[i] = *(const bf16x8*)(as + (wv * 64 + i * 16 + l15) * 32 + g * 8);
#pragma unroll
    for (int i = 0; i < 4; ++i)
#pragma unroll
      for (int j = 0; j < 4; ++j)
        acc[i][j] = __builtin_amdgcn_mfma_f32_16x16x32_bf16(afr[i], bfr[j], acc[i][j], 0, 0, 0);
  };

  gllA(0, 0);
  loadB(0);
  const int last = 7;                    // steps = 8
  for (int t = 0; t < 8; ++t) {
    const int cur = t & 1;
    gllA(1 - cur, (t + 1 < last) ? t + 1 : last);
    storeB(cur);
    loadB((t + 1 < last) ? t + 1 : last);
    asm volatile("s_waitcnt vmcnt(12) lgkmcnt(0)" ::: "memory");
    __builtin_amdgcn_s_barrier();
    __builtin_amdgcn_sched_barrier(0);
    comp(cur);
    __builtin_amdgcn_sched_barrier(0);
    __builtin_amdgcn_s_barrier();
  }
  asm volatile("s_waitcnt vmcnt(0) lgkmcnt(0)" ::: "memory");
  __builtin_amdgcn_s_barrier();

  float* sf = (float*)SH;                // [128][68]
#pragma unroll
  for (int h = 0; h < 2; ++h) {
    __syncthreads();
    if ((wv >> 1) == h) {
#pragma unroll
      for (int i = 0; i < 4; ++i)
#pragma unroll
        for (int j = 0; j < 4; ++j)
#pragma unroll
          for (int r = 0; r < 4; ++r)
            sf[((wv & 1) * 64 + i * 16 + g * 4 + r) * 68 + j * 16 + l15] = acc[i][j][r];
    }
    __syncthreads();
#pragma unroll
    for (int e = 0; e < 8; ++e) {
      int idx2 = tid + e * 256;
      int m = idx2 >> 4, c4 = (idx2 & 15) * 4;
      float4 v = *(const float4*)(sf + m * 68 + c4);
      *(float4*)(Cz + (size_t)(h * 128 + m) * ldc + col0 + c4) = v;
    }
  }
}

// ---------------- small kernels ----------------
// wave-per-row softmax over SUM of two G1 z-partials + bias.
// Extra block 2048 zeroes cs + scal (before colsum/make_sp/G2/combine3 use them).
__launch_bounds__(256)
__global__ void softmax_rows(const float* __restrict__ lg, float* __restrict__ io,
                             const float* __restrict__ bias,
                             float* __restrict__ cs, float* __restrict__ scal) {
  if (blockIdx.x == 2048) {
    int t = threadIdx.x;
    float4 z = {0.f, 0.f, 0.f, 0.f};
    if (t < 64) ((float4*)cs)[t] = z;
    else if (t == 64) ((float4*)scal)[0] = z;   // scal[0..3]
    return;
  }
  int wv = threadIdx.x >> 6, lane = threadIdx.x & 63;
  int n = blockIdx.x * 4 + wv;
  float4 b4 = ((const float4*)bias)[lane];
  float4 p0 = ((const float4*)(lg + (size_t)n * Kk))[lane];
  float4 p1 = ((const float4*)(lg + 2097152 + (size_t)n * Kk))[lane];
  float4 x = {p0.x + p1.x + b4.x, p0.y + p1.y + b4.y,
              p0.z + p1.z + b4.z, p0.w + p1.w + b4.w};
  float m = fmaxf(fmaxf(x.x, x.y), fmaxf(x.z, x.w));
#pragma unroll
  for (int o = 32; o; o >>= 1) m = fmaxf(m, __shfl_xor(m, o));
  float4 e = {__expf(x.x - m), __expf(x.y - m), __expf(x.z - m), __expf(x.w - m)};
  float s = e.x + e.y + e.z + e.w;
#pragma unroll
  for (int o = 32; o; o >>= 1) s += __shfl_xor(s, o);
  float inv = 1.f / s;
  e.x *= inv; e.y *= inv; e.z *= inv; e.w *= inv;
  ((float4*)(io + (size_t)n * Kk))[lane] = e;
}

// colsum: 64 blocks x 128 rows; float4.
__launch_bounds__(256)
__global__ void colsum_k(const float* __restrict__ a, float* __restrict__ cs) {
  __shared__ float4 red[4][64];
  int t = threadIdx.x, rg = t >> 6, c = t & 63;
  size_t n0 = (size_t)blockIdx.x * 128 + rg * 32;
  float4 s = {0.f, 0.f, 0.f, 0.f};
  for (int i = 0; i < 32; ++i) {
    float4 v = ((const float4*)(a + (n0 + i) * Kk))[c];
    s.x += v.x; s.y += v.y; s.z += v.z; s.w += v.w;
  }
  red[rg][c] = s;
  __syncthreads();
  if (rg == 0) {
    float4 a1 = red[1][c], a2 = red[2][c], a3 = red[3][c];
    s.x += a1.x + a2.x + a3.x; s.y += a1.y + a2.y + a3.y;
    s.z += a1.z + a2.z + a3.z; s.w += a1.w + a2.w + a3.w;
    atomicAdd(&cs[c * 4 + 0], s.x); atomicAdd(&cs[c * 4 + 1], s.y);
    atomicAdd(&cs[c * 4 + 2], s.z); atomicAdd(&cs[c * 4 + 3], s.w);
  }
}

// spT panel (inv folded) + entropy. block p: rows [32p,32p+32), thread = k.
__launch_bounds__(256)
__global__ void make_sp_pan(const float* __restrict__ a, const float* __restrict__ cs,
                            u16* __restrict__ pan, float* __restrict__ ent_sum) {
  __shared__ float sr[4];
  int p = blockIdx.x, k = threadIdx.x;
  float inv = 1.f / (cs[k] + 1e-8f);
  int n0 = p * 32;
  float ent = 0.f;
  ushort8_t h[4];
#pragma unroll
  for (int q = 0; q < 4; ++q) {
#pragma unroll
    for (int j = 0; j < 8; ++j) {
      float v = a[(size_t)(n0 + q * 8 + j) * Kk + k] * inv;
      h[q][j] = f2bf(v);
      ent -= v * __logf(v + 1e-15f);
    }
  }
  u16* dst = pan + ((size_t)p * 256 + k) * 32;
  *(uint4*)(dst + 0)  = __builtin_bit_cast(uint4, h[0]);
  *(uint4*)(dst + 8)  = __builtin_bit_cast(uint4, h[1]);
  *(uint4*)(dst + 16) = __builtin_bit_cast(uint4, h[2]);
  *(uint4*)(dst + 24) = __builtin_bit_cast(uint4, h[3]);
#pragma unroll
  for (int o = 32; o; o >>= 1) ent += __shfl_xor(ent, o);
  if ((k & 63) == 0) sr[k >> 6] = ent;
  __syncthreads();
  if (k == 0) atomicAdd(ent_sum, sr[0] + sr[1] + sr[2] + sr[3]);
}

// sum 8 bf16 partials -> P panel (stride-32)
__launch_bounds__(256)
__global__ void combine_P(const u16* __restrict__ part, u16* __restrict__ pan) {
  int idx = blockIdx.x * 256 + threadIdx.x;      // 262144
  int m = idx >> 10, kk8 = idx & 1023;
  size_t off = (size_t)m * Nn + kk8 * 8;
  float8_t s = {0.f, 0.f, 0.f, 0.f, 0.f, 0.f, 0.f, 0.f};
#pragma unroll
  for (int z = 0; z < 8; ++z) {
    ushort8_t v = __builtin_bit_cast(ushort8_t,
        *(const uint4*)(part + (size_t)z * Kk * Nn + off));
#pragma unroll
    for (int j = 0; j < 8; ++j) s[j] += bf2f(v[j]);
  }
  ushort8_t h;
#pragma unroll
  for (int j = 0; j < 8; ++j) h[j] = f2bf(s[j]);
  int p = kk8 >> 2, c = (kk8 & 3) * 8;
  *(uint4*)(pan + ((size_t)p * 256 + m) * 32 + c) = __builtin_bit_cast(uint4, h);
}

// combine z-partials; inv_cs column scaling for ss/ap (R12/R15-refchecked).
__launch_bounds__(256)
__global__ void combine3(const float* __restrict__ fp_part, const float* __restrict__ ss_part,
                         const float* __restrict__ ap_part, const float* __restrict__ cs,
                         float* __restrict__ fpool, float* __restrict__ apool,
                         float* __restrict__ scal) {
  __shared__ float sr[4];
  int b = blockIdx.x, t = threadIdx.x;
  if (b < 512) {
    int i = b * 256 + t;
    float s = 0.f;
#pragma unroll
    for (int z = 0; z < 32; ++z) s += fp_part[z * 131072 + i];
    fpool[i] = s;
  } else if (b < 768) {
    int i = (b - 512) * 256 + t;
    float s = 0.f;
#pragma unroll
    for (int z = 0; z < 32; ++z) s += ss_part[z * 65536 + i];
    s *= 1.f / (cs[i & 255] + 1e-8f);
    float q = s * s;
#pragma unroll
    for (int o = 32; o; o >>= 1) q += __shfl_xor(q, o);
    if ((t & 63) == 0) sr[t >> 6] = q;
    __syncthreads();
    if (t == 0) atomicAdd(&scal[2], sr[0] + sr[1] + sr[2] + sr[3]);
  } else {
    int i = (b - 768) * 256 + t;
    float s = 0.f;
#pragma unroll
    for (int z = 0; z < 32; ++z) s += ap_part[z * 65536 + i];
    s *= 1.f / (cs[i & 255] + 1e-8f);
    apool[i] = s;
    if (i % 257 == 0) atomicAdd(&scal[3], s);
  }
}

__launch_bounds__(64)
__global__ void finalize_k(const float* __restrict__ scal,
                           float* __restrict__ olink, float* __restrict__ oent) {
  if (threadIdx.x == 0) {
    float val = scal[0] - 2.f * scal[3] + scal[2];
    *olink = sqrtf(fmaxf(val, 0.f)) / ((float)Nn * (float)Nn);
    *oent  = scal[1] / (float)Nn;
  }
}

// ---------------- launch ----------------
extern "C" void kernel_launch(void* const* d_in, const int* in_sizes, int n_in,
                              void* d_out, int out_size, void* d_ws, size_t ws_size,
                              hipStream_t stream) {
  const float* F    = (const float*)d_in[0];
  const float* Adj  = (const float*)d_in[1];
  const float* W    = (const float*)d_in[2];
  const float* bias = (const float*)d_in[3];
  float* out = (float*)d_out;
  char* ws = (char*)d_ws;

  u16*  parts   = (u16*)(ws + 0);           // 8 x 4 MB bf16 G2 linear partials
  u16*  spTpan  = (u16*)(ws + 33554432);    // 4 MB
  u16*  Ppan    = (u16*)(ws + 37748736);    // 4 MB
  float* lg_part = (float*)(ws + 41943040); // 16 MB (2 x 2097152 f32)
  float* fp_part = (float*)(ws + 58720256); // 16 MB (32 x 131072 f32)
  float* ss_part = (float*)(ws + 75497472); // 8 MB (32 x 65536 f32)
  float* ap_part = (float*)(ws + 83886080); // 8 MB (32 x 65536 f32)
  float* cs     = (float*)(ws + 92274688);  // 1 KB
  float* scal   = (float*)(ws + 92275712);  // [0]=sumA2 [1]=ent [2]=frob [3]=trace

  float* fpool  = out;
  float* assign = out + 131072;
  float* apool  = out + 2228224;
  float* olink  = out + 2293760;
  float* oent   = out + 2293761;

  // G1 fused: logit partials = F @ W (A reg-staged from F; z=2, 256 blocks)
  gemm1<<<dim3(4, 32, 2), 256, 0, stream>>>(F, W, lg_part, 2097152);
  softmax_rows<<<2049, 256, 0, stream>>>(lg_part, assign, bias, cs, scal);
  colsum_k<<<64, 256, 0, stream>>>(assign, cs);
  make_sp_pan<<<256, 256, 0, stream>>>(assign, cs, spTpan, &scal[1]);

  // G4+G5 merged: 384 blocks, z=32 each, one f32 hot path
  gemm45<<<384, 256, 0, stream>>>(spTpan, F, fp_part, assign, ss_part);

  // G2: P = spT @ A: 8 bf16 partials + fused sum(A^2), XCD-chunked, 4 blk/CU
  gemm2<true, 1, 4><<<dim3(128, 1, 8), 256, 0, stream>>>(
      spTpan, 256, Adj, Nn, parts, Nn, Nn / 8, (size_t)Kk * Nn, &scal[0], 1);
  combine_P<<<1024, 256, 0, stream>>>(parts, Ppan);

  // G3: apool raw partials = P @ assign (z=32, 128 blocks; inv folded later)
  gemm2<false, 0, 2><<<dim3(4, 1, 32), 256, 0, stream>>>(
      Ppan, 256, assign, Kk, ap_part, Kk, 256, 65536, nullptr, 1);

  combine3<<<1024, 256, 0, stream>>>(fp_part, ss_part, ap_part, cs, fpool, apool, scal);
  finalize_k<<<1, 64, 0, stream>>>(scal, olink, oent);
}